// Round 6
// baseline (325.673 us; speedup 1.0000x reference)
//
#include <hip/hip_runtime.h>
#include <cstdint>

typedef unsigned int u32;
typedef unsigned short u16;

#define N_NODES 100000
#define N_EDGES 3200000
#define F_IN 128
#define DIM 10
#define QB 16            // bf16 elems per padded q row -> 32B
#define HPAD 12          // f32 h2 row stride (48B) for the pool kernel
#define B_GRAPHS 1000
#define NBLK_N 391       // ceil(N/256) gemm blocks

// Bucketing: 391 buckets of 256 dst nodes each (dst>>8).
// k_front: in-LDS chunk sort + coalesced run copy-out (runs ~21 records).
// k_mid: sort bucket in LDS, layer1 gather, SOFTWARE grid barrier (all 391
// blocks statically co-resident: 74KB LDS -> 2 blk/CU -> 512 slots; VGPR
// capped by __launch_bounds__(512,4)), then layer2 gather from the SAME
// resident LDS sort. No cooperative API (graph-capture safe), no persist,
// no restage.
#define SHIFTC 8
#define NBINS 256        // dst & 255 within a bucket
#define NCB 391          // ceil(N/256)
#define CAPC 8960        // slots/bucket: mean 8184 + ~8.6 sigma
#define CHUNK_C 8192     // edges per bucketing block
#define NBLK_C 391       // ceil(E/CHUNK_C)
#define GSTRIDE 16       // cursor padding: one 64B line per cursor
#define SEGW 257         // segment-start words per bucket (fallback path)

__device__ __forceinline__ u16 f2b(float f) {           // f32 -> bf16 (RNE)
  union { float f; u32 i; } c; c.f = f;
  u32 r = c.i + 0x7FFFu + ((c.i >> 16) & 1u);
  return (u16)(r >> 16);
}
__device__ __forceinline__ float bl(u32 u) {            // low bf16 -> f32
  union { u32 i; float f; } c; c.i = u << 16; return c.f;
}
__device__ __forceinline__ float bh(u32 u) {            // high bf16 -> f32
  union { u32 i; float f; } c; c.i = u & 0xFFFF0000u; return c.f;
}

// ---- gemm1 body: 1 thread/node, wave-uniform W indexing (s_loads) ----
__device__ __forceinline__ void gemm_body(
    int bid, int tid,
    const float* __restrict__ x, const float* __restrict__ W,
    float* __restrict__ p1, u16* __restrict__ q1b)
{
  int i = bid * 256 + tid;
  if (i >= N_NODES) return;
  const float4* __restrict__ xr = (const float4*)(x + (size_t)i * F_IN);
  float ap[DIM], aq[DIM];
  #pragma unroll
  for (int j = 0; j < DIM; ++j) { ap[j] = 0.f; aq[j] = 0.f; }
  #pragma unroll 4
  for (int k4 = 0; k4 < F_IN / 4; ++k4) {
    float4 v = xr[k4];
    const float* __restrict__ w0 = W + (k4 * 4) * DIM;
    const float* __restrict__ w1 = W + (F_IN + k4 * 4) * DIM;
    #pragma unroll
    for (int j = 0; j < DIM; ++j) {
      ap[j] += v.x * w0[j] + v.y * w0[DIM + j] + v.z * w0[2 * DIM + j] + v.w * w0[3 * DIM + j];
      aq[j] += v.x * w1[j] + v.y * w1[DIM + j] + v.z * w1[2 * DIM + j] + v.w * w1[3 * DIM + j];
    }
  }
  float* pr = p1 + (size_t)i * DIM;
  #pragma unroll
  for (int j = 0; j < DIM; ++j) pr[j] = ap[j];
  u32* qr = (u32*)(q1b + (size_t)i * QB);
  uint4 v0; u32 v1;
  v0.x = (u32)f2b(aq[0]) | ((u32)f2b(aq[1]) << 16);
  v0.y = (u32)f2b(aq[2]) | ((u32)f2b(aq[3]) << 16);
  v0.z = (u32)f2b(aq[4]) | ((u32)f2b(aq[5]) << 16);
  v0.w = (u32)f2b(aq[6]) | ((u32)f2b(aq[7]) << 16);
  v1   = (u32)f2b(aq[8]) | ((u32)f2b(aq[9]) << 16);
  *(uint4*)qr = v0;
  qr[4] = v1;
}

// ---- bucketing body: partition edges into 391 ranges (256 dst each) ----
// Record: ((dst & 255) << 17) | src   (src < 2^17)
// In-LDS counting sort by bucket id, then coalesced run-copy to global.
__device__ __forceinline__ void coarse_body(
    int bid, int tid,
    const int* __restrict__ src, const int* __restrict__ dst,
    u32* __restrict__ gcurc, u32* __restrict__ coarse)
{
  __shared__ u32 srt[CHUNK_C];        // 32 KB: chunk sorted by bucket id
  __shared__ u32 segst[NCB + 1];      // 1.6 KB: local exclusive scan
  __shared__ u32 rank[NCB];           // 1.6 KB: hist, then scatter rank
  __shared__ u32 gbase[NCB];          // 1.6 KB: global base per bucket
  __shared__ u32 wtot[4];

  for (int t = tid; t < NCB; t += 256) rank[t] = 0u;
  __syncthreads();

  int base = bid * CHUNK_C;
  const int4* __restrict__ dst4 = (const int4*)dst;
  const int4* __restrict__ src4 = (const int4*)src;
  // pass 1: histogram (int4 loads: 4 edges/thread/iter, 4 indep atomics)
  #pragma unroll
  for (int it = 0; it < CHUNK_C / 1024; ++it) {
    int e = base + it * 1024 + tid * 4;
    if (e < N_EDGES) {     // N_EDGES % 4 == 0, e % 4 == 0 -> whole int4 ok
      int4 d = dst4[(base >> 2) + it * 256 + tid];
      atomicAdd(&rank[(u32)d.x >> SHIFTC], 1u);
      atomicAdd(&rank[(u32)d.y >> SHIFTC], 1u);
      atomicAdd(&rank[(u32)d.z >> SHIFTC], 1u);
      atomicAdd(&rank[(u32)d.w >> SHIFTC], 1u);
    }
  }
  __syncthreads();

  // exclusive scan of 391 bins: 4 bins/thread (threads 0..97) + wave scan
  u32 lh[4] = {0u, 0u, 0u, 0u};
  u32 lsum = 0u;
  if (tid < 98) {
    #pragma unroll
    for (int k = 0; k < 4; ++k) {
      int b4 = tid * 4 + k;
      lh[k] = (b4 < NCB) ? rank[b4] : 0u;
      lsum += lh[k];
    }
  }
  u32 v = lsum;
  #pragma unroll
  for (int off = 1; off < 64; off <<= 1) {
    u32 t = __shfl_up(v, off, 64);
    if ((tid & 63) >= off) v += t;
  }
  if ((tid & 63) == 63) wtot[tid >> 6] = v;
  __syncthreads();
  u32 wofs = 0u;
  #pragma unroll
  for (int w = 0; w < 3; ++w) if ((tid >> 6) > w) wofs += wtot[w];
  if (tid < 98) {
    u32 excl = wofs + v - lsum;      // exclusive prefix across threads
    #pragma unroll
    for (int k = 0; k < 4; ++k) {
      int b4 = tid * 4 + k;
      if (b4 < NCB) segst[b4] = excl;
      excl += lh[k];
    }
    if (tid == 97) segst[NCB] = excl;      // chunk total
  }
  __syncthreads();

  // reserve global space per bucket; reset rank for the scatter pass
  for (int t = tid; t < NCB; t += 256) {
    u32 c = segst[t + 1] - segst[t];
    gbase[t] = c ? atomicAdd(&gcurc[t * GSTRIDE], c) : 0u;
    rank[t] = 0u;
  }
  __syncthreads();

  // pass 2: scatter into LDS (sorted by bucket id)
  #pragma unroll
  for (int it = 0; it < CHUNK_C / 1024; ++it) {
    int e = base + it * 1024 + tid * 4;
    if (e < N_EDGES) {
      int4 d = dst4[(base >> 2) + it * 256 + tid];
      int4 s = src4[(base >> 2) + it * 256 + tid];
      #pragma unroll
      for (int q = 0; q < 4; ++q) {
        u32 dd = (u32)((q == 0) ? d.x : (q == 1) ? d.y : (q == 2) ? d.z : d.w);
        u32 ss = (u32)((q == 0) ? s.x : (q == 1) ? s.y : (q == 2) ? s.z : s.w);
        u32 cb = dd >> SHIFTC;
        u32 pos = segst[cb] + atomicAdd(&rank[cb], 1u);
        srt[pos] = ((dd & (NBINS - 1u)) << 17) | ss;   // pos < CHUNK_C always
      }
    }
  }
  __syncthreads();

  // phase W: 16-lane groups copy per-bucket runs (contiguous -> coalesced)
  int grp = tid >> 4, lane = tid & 15;
  for (int cb = grp; cb < NCB; cb += 16) {
    u32 st = segst[cb];
    u32 cnt = segst[cb + 1] - st;
    u32 gb = gbase[cb];
    for (u32 r = lane; r < cnt; r += 16u) {
      u32 p = gb + r;
      if (p < CAPC)     // statistically impossible; memory-safety only
        coarse[(size_t)cb * CAPC + p] = srt[st + r];
    }
  }
}

// Fused front: blocks [0,NBLK_C) bucket edges, [NBLK_C,+NBLK_N) run gemm1.
__global__ __launch_bounds__(256) void k_front(
    const int* __restrict__ src, const int* __restrict__ dst,
    u32* __restrict__ gcurc, u32* __restrict__ coarse,
    const float* __restrict__ x, const float* __restrict__ W,
    float* __restrict__ p1, u16* __restrict__ q1b)
{
  if (blockIdx.x < NBLK_C)
    coarse_body(blockIdx.x, threadIdx.x, src, dst, gcurc, coarse);
  else
    gemm_body(blockIdx.x - NBLK_C, threadIdx.x, x, W, p1, q1b);
}

// ---- bucket counting-sort in LDS (512 threads, 256 bins) ----
__device__ __forceinline__ void sort_bucket(
    int tid, int n, const u32* __restrict__ rc,
    u32* lrec, u32* srt, u32* hist, u32* segst, u32* rank, u32* wtot)
{
  if (tid < NBINS) { hist[tid] = 0u; rank[tid] = 0u; }
  __syncthreads();
  for (int r = tid; r < n; r += 512) {
    u32 v = rc[r];
    lrec[r] = v;
    atomicAdd(&hist[(v >> 17) & (NBINS - 1u)], 1u);
  }
  __syncthreads();
  u32 h = 0u, v = 0u;
  if (tid < NBINS) {
    h = hist[tid]; v = h;
    #pragma unroll
    for (int off = 1; off < 64; off <<= 1) {
      u32 t = __shfl_up(v, off, 64);
      if ((tid & 63) >= off) v += t;
    }
    if ((tid & 63) == 63) wtot[tid >> 6] = v;
  }
  __syncthreads();
  if (tid < NBINS) {
    u32 wofs = 0u;
    #pragma unroll
    for (int w2 = 0; w2 < 3; ++w2) if ((tid >> 6) > w2) wofs += wtot[w2];
    segst[tid] = wofs + v - h;
  }
  if (tid == 0) segst[NBINS] = wtot[0] + wtot[1] + wtot[2] + wtot[3];
  __syncthreads();
  for (int r = tid; r < n; r += 512) {
    u32 vv = lrec[r];
    u32 dl = (vv >> 17) & (NBINS - 1u);
    u32 pos = segst[dl] + atomicAdd(&rank[dl], 1u);
    srt[pos] = vv & 0x1FFFFu;
  }
  __syncthreads();
}

// Segment gather: assumes srt (LDS sorted src), st, en, l in scope.
#define SEG_GATHER(QSRC)                                                      \
  float s[DIM];                                                               \
  _Pragma("unroll")                                                           \
  for (int j = 0; j < DIM; ++j) s[j] = 0.f;                                   \
  {                                                                           \
    int k = st + l;                                                           \
    for (; k + 8 < en; k += 16) {                                             \
      int s0 = (int)srt[k], s1 = (int)srt[k + 8];                             \
      const u32* __restrict__ q0 = (const u32*)(QSRC + (size_t)s0 * QB);      \
      const u32* __restrict__ q1 = (const u32*)(QSRC + (size_t)s1 * QB);      \
      uint4 A0 = *(const uint4*)q0; u32 B0 = q0[4];                           \
      uint4 A1 = *(const uint4*)q1; u32 B1 = q1[4];                           \
      s[0] += bl(A0.x) + bl(A1.x); s[1] += bh(A0.x) + bh(A1.x);               \
      s[2] += bl(A0.y) + bl(A1.y); s[3] += bh(A0.y) + bh(A1.y);               \
      s[4] += bl(A0.z) + bl(A1.z); s[5] += bh(A0.z) + bh(A1.z);               \
      s[6] += bl(A0.w) + bl(A1.w); s[7] += bh(A0.w) + bh(A1.w);               \
      s[8] += bl(B0) + bl(B1);     s[9] += bh(B0) + bh(B1);                   \
    }                                                                         \
    if (k < en) {                                                             \
      int s0 = (int)srt[k];                                                   \
      const u32* __restrict__ q0 = (const u32*)(QSRC + (size_t)s0 * QB);      \
      uint4 A0 = *(const uint4*)q0; u32 B0 = q0[4];                           \
      s[0] += bl(A0.x); s[1] += bh(A0.x);                                     \
      s[2] += bl(A0.y); s[3] += bh(A0.y);                                     \
      s[4] += bl(A0.z); s[5] += bh(A0.z);                                     \
      s[6] += bl(A0.w); s[7] += bh(A0.w);                                     \
      s[8] += bl(B0);   s[9] += bh(B0);                                       \
    }                                                                         \
  }                                                                           \
  _Pragma("unroll")                                                           \
  for (int m = 1; m < 8; m <<= 1) {                                           \
    _Pragma("unroll")                                                         \
    for (int j = 0; j < DIM; ++j) s[j] += __shfl_xor(s[j], m, 8);             \
  }

// Layer-1 gather + epilogue: h = relu(p1+mean); (p2,q2) = h @ W2.
__device__ __forceinline__ void lay1_gather(
    int c, int tid, const u32* srt, const u32* segst, const float* w,
    const float* __restrict__ p1, const u16* __restrict__ q1b,
    float* __restrict__ p2, u16* __restrict__ q2b)
{
  int g0 = tid >> 3, l = tid & 7;
  for (int rd = 0; rd < NBINS / 64; ++rd) {
    int g2 = rd * 64 + g0;
    int st = (int)segst[g2], en = (int)segst[g2 + 1];
    SEG_GATHER(q1b)
    if (l == 0) {
      int i = c * NBINS + g2;
      if (i < N_NODES) {
        float inv = 1.0f / fmaxf((float)(en - st), 1.0f);
        const float* __restrict__ pr = p1 + (size_t)i * DIM;
        float h[DIM];
        #pragma unroll
        for (int j = 0; j < DIM; ++j) h[j] = fmaxf(pr[j] + s[j] * inv, 0.0f);
        float aa[DIM], bb[DIM];
        #pragma unroll
        for (int j = 0; j < DIM; ++j) {
          float t0 = 0.f, t1 = 0.f;
          #pragma unroll
          for (int kk = 0; kk < DIM; ++kk) {
            t0 += h[kk] * w[kk * DIM + j];
            t1 += h[kk] * w[(DIM + kk) * DIM + j];
          }
          aa[j] = t0; bb[j] = t1;
        }
        float* po = p2 + (size_t)i * DIM;
        #pragma unroll
        for (int j = 0; j < DIM; ++j) po[j] = aa[j];
        u32* qo = (u32*)(q2b + (size_t)i * QB);
        uint4 v0; u32 v1;
        v0.x = (u32)f2b(bb[0]) | ((u32)f2b(bb[1]) << 16);
        v0.y = (u32)f2b(bb[2]) | ((u32)f2b(bb[3]) << 16);
        v0.z = (u32)f2b(bb[4]) | ((u32)f2b(bb[5]) << 16);
        v0.w = (u32)f2b(bb[6]) | ((u32)f2b(bb[7]) << 16);
        v1   = (u32)f2b(bb[8]) | ((u32)f2b(bb[9]) << 16);
        *(uint4*)qo = v0;
        qo[4] = v1;
      }
    }
  }
}

// Layer-2 gather + epilogue: h2 = p2 + mean (f32, stride 12).
__device__ __forceinline__ void lay2_gather(
    int c, int tid, const u32* srt, const u32* segst,
    const float* __restrict__ p2, const u16* __restrict__ q2b,
    float* __restrict__ h2)
{
  int g0 = tid >> 3, l = tid & 7;
  for (int rd = 0; rd < NBINS / 64; ++rd) {
    int g2 = rd * 64 + g0;
    int st = (int)segst[g2], en = (int)segst[g2 + 1];
    SEG_GATHER(q2b)
    if (l == 0) {
      int i = c * NBINS + g2;
      if (i < N_NODES) {
        float inv = 1.0f / fmaxf((float)(en - st), 1.0f);
        const float* __restrict__ pr = p2 + (size_t)i * DIM;
        float* ho = h2 + (size_t)i * HPAD;
        #pragma unroll
        for (int j = 0; j < DIM; ++j) ho[j] = pr[j] + s[j] * inv;
      }
    }
  }
}

// Fused mid: sort bucket once in LDS; layer1; SOFTWARE grid barrier
// (all 391 blocks co-resident by construction: 74KB LDS -> 2 blocks/CU
// -> 512 slots >= 391; __launch_bounds__(512,4) caps VGPR <= 128 so the
// RF also fits 2 blocks/CU); layer2 from the same resident LDS sort.
__global__ __launch_bounds__(512, 4) void k_mid(
    const u32* __restrict__ gcurc, const u32* __restrict__ coarse,
    const float* __restrict__ p1, const u16* __restrict__ q1b,
    const float* __restrict__ W2, float* __restrict__ p2,
    u16* __restrict__ q2b, float* __restrict__ h2, u32* bar)
{
  __shared__ u32 lrec[CAPC];          // 35 KB
  __shared__ u32 srt[CAPC];           // 35 KB
  __shared__ u32 hist[NBINS];
  __shared__ u32 segst[NBINS + 1];
  __shared__ u32 rank[NBINS];
  __shared__ u32 wtot[4];
  __shared__ float w[2 * DIM * DIM];
  int tid = threadIdx.x, c = blockIdx.x;
  for (int t = tid; t < 2 * DIM * DIM; t += 512) w[t] = W2[t];
  int n = min((int)gcurc[c * GSTRIDE], CAPC);
  sort_bucket(tid, n, coarse + (size_t)c * CAPC, lrec, srt, hist, segst, rank, wtot);
  lay1_gather(c, tid, srt, segst, w, p1, q1b, p2, q2b);
  // ---- device-wide barrier (arrive + spin), graph-capture safe ----
  __syncthreads();                    // all block stores issued (vmcnt drain)
  __threadfence();                    // agent-scope release (L2 writeback)
  if (tid == 0) {
    atomicAdd(bar, 1u);               // device-scope arrive
    while (__hip_atomic_load(bar, __ATOMIC_RELAXED, __HIP_MEMORY_SCOPE_AGENT)
           < (u32)NCB)
      __builtin_amdgcn_s_sleep(32);
  }
  __syncthreads();
  __threadfence();                    // acquire (invalidate stale caches)
  lay2_gather(c, tid, srt, segst, p2, q2b, h2);
}

// Fallback split path (used only if occupancy query denies co-residency).
__global__ __launch_bounds__(512, 4) void k_lay1f(
    const u32* __restrict__ gcurc, u32* __restrict__ coarse,
    const float* __restrict__ p1, const u16* __restrict__ q1b,
    const float* __restrict__ W2, float* __restrict__ p2,
    u16* __restrict__ q2b, u32* __restrict__ segg)
{
  __shared__ u32 lrec[CAPC];
  __shared__ u32 srt[CAPC];
  __shared__ u32 hist[NBINS];
  __shared__ u32 segst[NBINS + 1];
  __shared__ u32 rank[NBINS];
  __shared__ u32 wtot[4];
  __shared__ float w[2 * DIM * DIM];
  int tid = threadIdx.x, c = blockIdx.x;
  for (int t = tid; t < 2 * DIM * DIM; t += 512) w[t] = W2[t];
  int n = min((int)gcurc[c * GSTRIDE], CAPC);
  sort_bucket(tid, n, coarse + (size_t)c * CAPC, lrec, srt, hist, segst, rank, wtot);
  for (int r = tid; r < n; r += 512) coarse[(size_t)c * CAPC + r] = srt[r];
  if (tid <= NBINS) segg[(size_t)c * SEGW + tid] = segst[tid];
  lay1_gather(c, tid, srt, segst, w, p1, q1b, p2, q2b);
}

__global__ __launch_bounds__(512, 4) void k_lay2f(
    const u32* __restrict__ gcurc, const u32* __restrict__ coarse,
    const u32* __restrict__ segg,
    const float* __restrict__ p2, const u16* __restrict__ q2b,
    float* __restrict__ h2)
{
  __shared__ u32 srt[CAPC];
  __shared__ u32 segst[NBINS + 1];
  int tid = threadIdx.x, c = blockIdx.x;
  if (tid <= NBINS) segst[tid] = segg[(size_t)c * SEGW + tid];
  int n = min((int)gcurc[c * GSTRIDE], CAPC);
  const u32* __restrict__ rc = coarse + (size_t)c * CAPC;
  for (int r = tid; r < n; r += 512) srt[r] = rc[r];
  __syncthreads();
  lay2_gather(c, tid, srt, segst, p2, q2b, h2);
}

// one wave per graph: binary-search node range in sorted batch, mean-pool,
// dot with Wfc, sigmoid -> out[b]. Zero atomics.
__global__ __launch_bounds__(64) void k_pool(
    const float* __restrict__ h2, const int* __restrict__ batch,
    const float* __restrict__ Wfc, float* __restrict__ out)
{
  int b = blockIdx.x;
  int lo = 0, hi = N_NODES;
  while (lo < hi) { int m = (lo + hi) >> 1; if (batch[m] < b) lo = m + 1; else hi = m; }
  int start = lo;
  hi = N_NODES;
  while (lo < hi) { int m = (lo + hi) >> 1; if (batch[m] < b + 1) lo = m + 1; else hi = m; }
  int end = lo;
  float sum[DIM];
  #pragma unroll
  for (int j = 0; j < DIM; ++j) sum[j] = 0.f;
  for (int r = start + (int)threadIdx.x; r < end; r += 64) {
    const float4* __restrict__ p = (const float4*)(h2 + (size_t)r * HPAD);
    float4 r0 = p[0], r1 = p[1];
    float2 r2 = *(const float2*)(h2 + (size_t)r * HPAD + 8);
    sum[0] += r0.x; sum[1] += r0.y; sum[2] += r0.z; sum[3] += r0.w;
    sum[4] += r1.x; sum[5] += r1.y; sum[6] += r1.z; sum[7] += r1.w;
    sum[8] += r2.x; sum[9] += r2.y;
  }
  #pragma unroll
  for (int m = 1; m < 64; m <<= 1) {
    #pragma unroll
    for (int j = 0; j < DIM; ++j) sum[j] += __shfl_xor(sum[j], m, 64);
  }
  if (threadIdx.x == 0) {
    float inv = 1.0f / fmaxf((float)(end - start), 1.0f);
    float acc = 0.f;
    #pragma unroll
    for (int j = 0; j < DIM; ++j) acc += sum[j] * inv * Wfc[j];
    out[b] = 1.0f / (1.0f + expf(-acc));
  }
}

extern "C" void kernel_launch(void* const* d_in, const int* in_sizes, int n_in,
                              void* d_out, int out_size, void* d_ws, size_t ws_size,
                              hipStream_t stream)
{
  const float* x     = (const float*)d_in[0];
  const int*   ei    = (const int*)d_in[1];
  const int*   batch = (const int*)d_in[2];
  const float* W1    = (const float*)d_in[3];
  const float* W2    = (const float*)d_in[4];
  const float* Wfc   = (const float*)d_in[5];
  float* out = (float*)d_out;

  const int* src = ei;            // edge_index[0]
  const int* dst = ei + N_EDGES;  // edge_index[1]

  // ---- workspace layout (u32 element offsets), total ~33.6 MB ----
  u32* wsp = (u32*)d_ws;
  u32* gcurc  = wsp;                                  // 6,256 used
  u32* bar    = wsp + 6272;                           // barrier counter
  u32* coarse = wsp + 6400;                           // 391*8960 = 3,503,360
  u32* segg   = coarse + (size_t)NCB * CAPC;          // 391*257 (pad 100,608)
  u32* after  = segg + 100608;
  u16*   q1b = (u16*)after;                           // 800,000 u32
  float* p1  = (float*)(after + 800000);              // 1,000,000 u32
  u16*   q2b = (u16*)(after + 1800000);               // 800,000 u32
  float* p2  = (float*)(after + 2600000);             // 1,000,000 u32
  float* h2  = (float*)(after + 3600000);             // 1,200,000 u32

  // zero cursors + barrier (covers wsp[0..6400))
  hipMemsetAsync(wsp, 0, 6400 * sizeof(u32), stream);

  k_front<<<NBLK_C + NBLK_N, 256, 0, stream>>>(src, dst, gcurc, coarse,
                                               x, W1, p1, q1b);

  // static co-residency guarantee + host-side double-check (capture-safe)
  int dev = 0; hipGetDevice(&dev);
  int nCU = 0;
  hipDeviceGetAttribute(&nCU, hipDeviceAttributeMultiprocessorCount, dev);
  int nb = 0;
  hipOccupancyMaxActiveBlocksPerMultiprocessor(&nb, k_mid, 512, 0);
  bool fuse = (nb > 0) && ((long)nb * (long)nCU >= (long)NCB);

  if (fuse) {
    k_mid<<<NCB, 512, 0, stream>>>(gcurc, coarse, p1, q1b, W2, p2, q2b, h2, bar);
  } else {
    k_lay1f<<<NCB, 512, 0, stream>>>(gcurc, coarse, p1, q1b, W2, p2, q2b, segg);
    k_lay2f<<<NCB, 512, 0, stream>>>(gcurc, coarse, segg, p2, q2b, h2);
  }
  k_pool<<<B_GRAPHS, 64, 0, stream>>>(h2, batch, Wfc, out);
}

// Round 7
// 234.610 us; speedup vs baseline: 1.3881x; 1.3881x over previous
//
#include <hip/hip_runtime.h>
#include <cstdint>

typedef unsigned int u32;
typedef unsigned short u16;

#define N_NODES 100000
#define N_EDGES 3200000
#define F_IN 128
#define DIM 10
#define QB 16            // bf16 elems per padded q row -> 32B
#define B_GRAPHS 1000
#define NBLK_N 391       // ceil(N/256) gemm blocks

// Round-4 proven front: 782 buckets of 128 dst nodes (dst>>7), 391 chunk
// blocks, in-LDS chunk sort + coalesced run copy-out.
// Back half (NEW): layer2+pool algebraically collapsed. h2 only feeds
// mean_graph(h2)@Wfc, and everything after h=relu(...) is linear, so
// k_lay1 emits scalars y=h·(W2_top@Wfc), z=h·(W2_bot@Wfc) (8B/node);
// k_lay2 gathers the L2-resident 400KB z table at 4B/edge (no sort, no
// LDS staging, streams persisted sorted records) and atomicAdds per-graph;
// k_pool = 1000 threads of sigmoid(gacc/|Vg|).
#define SHIFTC 7
#define NBINS 128        // dst & 127 within a bucket
#define NCB 782          // ceil(N/128)
#define CAPC 4608        // slots/bucket: mean 4092 + 8 sigma
#define CHUNK_C 8192     // edges per bucketing block
#define NBLK_C 391       // ceil(E/CHUNK_C)
#define GSTRIDE 16       // cursor padding: one 64B line per cursor
#define SEGW 129         // segment-start words per bucket (NBINS+1)

__device__ __forceinline__ u16 f2b(float f) {           // f32 -> bf16 (RNE)
  union { float f; u32 i; } c; c.f = f;
  u32 r = c.i + 0x7FFFu + ((c.i >> 16) & 1u);
  return (u16)(r >> 16);
}
__device__ __forceinline__ float bl(u32 u) {            // low bf16 -> f32
  union { u32 i; float f; } c; c.i = u << 16; return c.f;
}
__device__ __forceinline__ float bh(u32 u) {            // high bf16 -> f32
  union { u32 i; float f; } c; c.i = u & 0xFFFF0000u; return c.f;
}

// ---- gemm1 body: 1 thread/node, wave-uniform W indexing (s_loads) ----
__device__ __forceinline__ void gemm_body(
    int bid, int tid,
    const float* __restrict__ x, const float* __restrict__ W,
    float* __restrict__ p1, u16* __restrict__ q1b)
{
  int i = bid * 256 + tid;
  if (i >= N_NODES) return;
  const float4* __restrict__ xr = (const float4*)(x + (size_t)i * F_IN);
  float ap[DIM], aq[DIM];
  #pragma unroll
  for (int j = 0; j < DIM; ++j) { ap[j] = 0.f; aq[j] = 0.f; }
  #pragma unroll 4
  for (int k4 = 0; k4 < F_IN / 4; ++k4) {
    float4 v = xr[k4];
    const float* __restrict__ w0 = W + (k4 * 4) * DIM;
    const float* __restrict__ w1 = W + (F_IN + k4 * 4) * DIM;
    #pragma unroll
    for (int j = 0; j < DIM; ++j) {
      ap[j] += v.x * w0[j] + v.y * w0[DIM + j] + v.z * w0[2 * DIM + j] + v.w * w0[3 * DIM + j];
      aq[j] += v.x * w1[j] + v.y * w1[DIM + j] + v.z * w1[2 * DIM + j] + v.w * w1[3 * DIM + j];
    }
  }
  float* pr = p1 + (size_t)i * DIM;
  #pragma unroll
  for (int j = 0; j < DIM; ++j) pr[j] = ap[j];
  u32* qr = (u32*)(q1b + (size_t)i * QB);
  uint4 v0; u32 v1;
  v0.x = (u32)f2b(aq[0]) | ((u32)f2b(aq[1]) << 16);
  v0.y = (u32)f2b(aq[2]) | ((u32)f2b(aq[3]) << 16);
  v0.z = (u32)f2b(aq[4]) | ((u32)f2b(aq[5]) << 16);
  v0.w = (u32)f2b(aq[6]) | ((u32)f2b(aq[7]) << 16);
  v1   = (u32)f2b(aq[8]) | ((u32)f2b(aq[9]) << 16);
  *(uint4*)qr = v0;
  qr[4] = v1;
}

// ---- bucketing body: partition edges into 782 ranges (128 dst each) ----
// Record: ((dst & 127) << 17) | src   (src < 2^17)
// In-LDS counting sort by bucket id, then coalesced run-copy to global.
__device__ __forceinline__ void coarse_body(
    int bid, int tid,
    const int* __restrict__ src, const int* __restrict__ dst,
    u32* __restrict__ gcurc, u32* __restrict__ coarse)
{
  __shared__ u32 srt[CHUNK_C];        // 32 KB: chunk sorted by bucket id
  __shared__ u32 segst[NCB + 1];      // 3.1 KB: local exclusive scan
  __shared__ u32 rank[NCB];           // 3.1 KB: hist, then scatter rank
  __shared__ u32 gbase[NCB];          // 3.1 KB: global base per bucket
  __shared__ u32 wtot[4];

  for (int t = tid; t < NCB; t += 256) rank[t] = 0u;
  __syncthreads();

  int base = bid * CHUNK_C;
  const int4* __restrict__ dst4 = (const int4*)dst;
  const int4* __restrict__ src4 = (const int4*)src;
  // pass 1: histogram (int4 loads: 4 edges/thread/iter, 4 indep atomics)
  #pragma unroll
  for (int it = 0; it < CHUNK_C / 1024; ++it) {
    int e = base + it * 1024 + tid * 4;
    if (e < N_EDGES) {     // N_EDGES % 4 == 0, e % 4 == 0 -> whole int4 ok
      int4 d = dst4[(base >> 2) + it * 256 + tid];
      atomicAdd(&rank[(u32)d.x >> SHIFTC], 1u);
      atomicAdd(&rank[(u32)d.y >> SHIFTC], 1u);
      atomicAdd(&rank[(u32)d.z >> SHIFTC], 1u);
      atomicAdd(&rank[(u32)d.w >> SHIFTC], 1u);
    }
  }
  __syncthreads();

  // exclusive scan of 782 bins: 4 bins/thread (threads 0..195) + wave scan
  u32 lh[4] = {0u, 0u, 0u, 0u};
  u32 lsum = 0u;
  if (tid < 196) {
    #pragma unroll
    for (int k = 0; k < 4; ++k) {
      int b4 = tid * 4 + k;
      lh[k] = (b4 < NCB) ? rank[b4] : 0u;
      lsum += lh[k];
    }
  }
  u32 v = lsum;
  #pragma unroll
  for (int off = 1; off < 64; off <<= 1) {
    u32 t = __shfl_up(v, off, 64);
    if ((tid & 63) >= off) v += t;
  }
  if ((tid & 63) == 63) wtot[tid >> 6] = v;
  __syncthreads();
  u32 wofs = 0u;
  #pragma unroll
  for (int w = 0; w < 3; ++w) if ((tid >> 6) > w) wofs += wtot[w];
  if (tid < 196) {
    u32 excl = wofs + v - lsum;      // exclusive prefix across threads
    #pragma unroll
    for (int k = 0; k < 4; ++k) {
      int b4 = tid * 4 + k;
      if (b4 < NCB) segst[b4] = excl;
      excl += lh[k];
    }
    if (tid == 195) segst[NCB] = excl;     // chunk total
  }
  __syncthreads();

  // reserve global space per bucket; reset rank for the scatter pass
  for (int t = tid; t < NCB; t += 256) {
    u32 c = segst[t + 1] - segst[t];
    gbase[t] = c ? atomicAdd(&gcurc[t * GSTRIDE], c) : 0u;
    rank[t] = 0u;
  }
  __syncthreads();

  // pass 2: scatter into LDS (sorted by bucket id)
  #pragma unroll
  for (int it = 0; it < CHUNK_C / 1024; ++it) {
    int e = base + it * 1024 + tid * 4;
    if (e < N_EDGES) {
      int4 d = dst4[(base >> 2) + it * 256 + tid];
      int4 s = src4[(base >> 2) + it * 256 + tid];
      #pragma unroll
      for (int q = 0; q < 4; ++q) {
        u32 dd = (u32)((q == 0) ? d.x : (q == 1) ? d.y : (q == 2) ? d.z : d.w);
        u32 ss = (u32)((q == 0) ? s.x : (q == 1) ? s.y : (q == 2) ? s.z : s.w);
        u32 cb = dd >> SHIFTC;
        u32 pos = segst[cb] + atomicAdd(&rank[cb], 1u);
        srt[pos] = ((dd & (NBINS - 1u)) << 17) | ss;   // pos < CHUNK_C always
      }
    }
  }
  __syncthreads();

  // phase W: 16-lane groups copy per-bucket runs (contiguous -> coalesced)
  int grp = tid >> 4, lane = tid & 15;
  for (int cb = grp; cb < NCB; cb += 16) {
    u32 st = segst[cb];
    u32 cnt = segst[cb + 1] - st;
    u32 gb = gbase[cb];
    for (u32 r = lane; r < cnt; r += 16u) {
      u32 p = gb + r;
      if (p < CAPC)     // statistically impossible; memory-safety only
        coarse[(size_t)cb * CAPC + p] = srt[st + r];
    }
  }
}

// Fused front: blocks [0,NBLK_C) bucket edges, [NBLK_C,+NBLK_N) run gemm1.
__global__ __launch_bounds__(256) void k_front(
    const int* __restrict__ src, const int* __restrict__ dst,
    u32* __restrict__ gcurc, u32* __restrict__ coarse,
    const float* __restrict__ x, const float* __restrict__ W,
    float* __restrict__ p1, u16* __restrict__ q1b)
{
  if (blockIdx.x < NBLK_C)
    coarse_body(blockIdx.x, threadIdx.x, src, dst, gcurc, coarse);
  else
    gemm_body(blockIdx.x - NBLK_C, threadIdx.x, x, W, p1, q1b);
}

// Segment gather: assumes srt (LDS sorted src), st, en, l in scope.
#define SEG_GATHER(QSRC)                                                      \
  float s[DIM];                                                               \
  _Pragma("unroll")                                                           \
  for (int j = 0; j < DIM; ++j) s[j] = 0.f;                                   \
  {                                                                           \
    int k = st + l;                                                           \
    for (; k + 8 < en; k += 16) {                                             \
      int s0 = (int)srt[k], s1 = (int)srt[k + 8];                             \
      const u32* __restrict__ q0 = (const u32*)(QSRC + (size_t)s0 * QB);      \
      const u32* __restrict__ q1 = (const u32*)(QSRC + (size_t)s1 * QB);      \
      uint4 A0 = *(const uint4*)q0; u32 B0 = q0[4];                           \
      uint4 A1 = *(const uint4*)q1; u32 B1 = q1[4];                           \
      s[0] += bl(A0.x) + bl(A1.x); s[1] += bh(A0.x) + bh(A1.x);               \
      s[2] += bl(A0.y) + bl(A1.y); s[3] += bh(A0.y) + bh(A1.y);               \
      s[4] += bl(A0.z) + bl(A1.z); s[5] += bh(A0.z) + bh(A1.z);               \
      s[6] += bl(A0.w) + bl(A1.w); s[7] += bh(A0.w) + bh(A1.w);               \
      s[8] += bl(B0) + bl(B1);     s[9] += bh(B0) + bh(B1);                   \
    }                                                                         \
    if (k < en) {                                                             \
      int s0 = (int)srt[k];                                                   \
      const u32* __restrict__ q0 = (const u32*)(QSRC + (size_t)s0 * QB);      \
      uint4 A0 = *(const uint4*)q0; u32 B0 = q0[4];                           \
      s[0] += bl(A0.x); s[1] += bh(A0.x);                                     \
      s[2] += bl(A0.y); s[3] += bh(A0.y);                                     \
      s[4] += bl(A0.z); s[5] += bh(A0.z);                                     \
      s[6] += bl(A0.w); s[7] += bh(A0.w);                                     \
      s[8] += bl(B0);   s[9] += bh(B0);                                       \
    }                                                                         \
  }                                                                           \
  _Pragma("unroll")                                                           \
  for (int m = 1; m < 8; m <<= 1) {                                           \
    _Pragma("unroll")                                                         \
    for (int j = 0; j < DIM; ++j) s[j] += __shfl_xor(s[j], m, 8);             \
  }

// Layer 1: counting-sort a whole 128-dst bucket (~4092 records) in LDS,
// persist sorted order (coarse in place + segg) for k_lay2, gather,
// epilogue h = relu(p1+mean); y = h.wv1, z = h.wv2 (folded W2@Wfc).
__global__ __launch_bounds__(512) void k_lay1(
    const u32* __restrict__ gcurc, u32* __restrict__ coarse,
    const float* __restrict__ p1, const u16* __restrict__ q1b,
    const float* __restrict__ W2, const float* __restrict__ Wfc,
    float* __restrict__ y, float* __restrict__ z,
    u32* __restrict__ segg)
{
  __shared__ u32 lrec[CAPC];          // 18 KB
  __shared__ u32 srt[CAPC];           // 18 KB
  __shared__ u32 hist[NBINS];
  __shared__ u32 segst[NBINS + 1];
  __shared__ u32 rank[NBINS];
  __shared__ u32 wtot[2];
  __shared__ float wv[2 * DIM];       // wv[k] = sum_j W2[k][j] * Wfc[j]
  int tid = threadIdx.x;
  int c = blockIdx.x;
  if (tid < 2 * DIM) {
    float sacc = 0.f;
    #pragma unroll
    for (int j = 0; j < DIM; ++j) sacc += W2[tid * DIM + j] * Wfc[j];
    wv[tid] = sacc;
  }
  if (tid < NBINS) { hist[tid] = 0u; rank[tid] = 0u; }
  __syncthreads();
  int n = min((int)gcurc[c * GSTRIDE], CAPC);
  const u32* __restrict__ rc = coarse + (size_t)c * CAPC;
  for (int r = tid; r < n; r += 512) {
    u32 v = rc[r];
    lrec[r] = v;
    atomicAdd(&hist[(v >> 17) & (NBINS - 1u)], 1u);
  }
  __syncthreads();
  // 128-bin exclusive scan: intra-wave shfl scan + cross-wave offset
  if (tid < NBINS) {
    u32 h = hist[tid];
    u32 v = h;
    #pragma unroll
    for (int off = 1; off < 64; off <<= 1) {
      u32 t = __shfl_up(v, off, 64);
      if ((tid & 63) >= off) v += t;
    }
    if ((tid & 63) == 63) wtot[tid >> 6] = v;
    segst[tid] = v - h;
  }
  __syncthreads();
  if (tid >= 64 && tid < NBINS) segst[tid] += wtot[0];
  if (tid == 0) segst[NBINS] = wtot[0] + wtot[1];
  __syncthreads();
  for (int r = tid; r < n; r += 512) {
    u32 v = lrec[r];
    u32 dl = (v >> 17) & (NBINS - 1u);
    u32 pos = segst[dl] + atomicAdd(&rank[dl], 1u);
    srt[pos] = v & 0x1FFFFu;
  }
  __syncthreads();
  // persist sorted order (k_lay2 streams it; no second sort)
  for (int r = tid; r < n; r += 512) coarse[(size_t)c * CAPC + r] = srt[r];
  if (tid <= NBINS) segg[(size_t)c * SEGW + tid] = segst[tid];
  // gather + epilogue: 64 groups of 8 lanes, 2 rounds cover 128 nodes
  int g0 = tid >> 3, l = tid & 7;
  #pragma unroll
  for (int rd = 0; rd < 2; ++rd) {
    int g2 = rd * 64 + g0;
    int st = (int)segst[g2], en = (int)segst[g2 + 1];
    SEG_GATHER(q1b)
    if (l == 0) {
      int i = c * NBINS + g2;
      if (i < N_NODES) {
        float inv = 1.0f / fmaxf((float)(en - st), 1.0f);
        const float* __restrict__ pr = p1 + (size_t)i * DIM;
        float yv = 0.f, zv = 0.f;
        #pragma unroll
        for (int j = 0; j < DIM; ++j) {
          float h = fmaxf(pr[j] + s[j] * inv, 0.0f);
          yv += h * wv[j];
          zv += h * wv[DIM + j];
        }
        y[i] = yv;
        z[i] = zv;
      }
    }
  }
}

// Layer 2 + pool-accumulate: stream persisted sorted records straight from
// global (read once, coalesced within segments), gather scalar z[src] from
// the L2-resident 400KB table, per-graph atomicAdd of y + mean(z).
__global__ __launch_bounds__(256) void k_lay2(
    const u32* __restrict__ gcurc, const u32* __restrict__ coarse,
    const u32* __restrict__ segg,
    const float* __restrict__ y, const float* __restrict__ z,
    const int* __restrict__ batch, float* __restrict__ gacc)
{
  __shared__ u32 segst[NBINS + 1];
  int tid = threadIdx.x, c = blockIdx.x;
  if (tid <= NBINS) segst[tid] = segg[(size_t)c * SEGW + tid];
  __syncthreads();
  const u32* __restrict__ rc = coarse + (size_t)c * CAPC;
  int g0 = tid >> 3, l = tid & 7;
  #pragma unroll
  for (int rd = 0; rd < 4; ++rd) {    // 32 groups x 4 rounds = 128 nodes
    int loc = rd * 32 + g0;
    int st = (int)segst[loc], en = (int)segst[loc + 1];
    float sc = 0.f;
    for (int k = st + l; k < en; k += 8) sc += z[rc[k]];
    #pragma unroll
    for (int m = 1; m < 8; m <<= 1) sc += __shfl_xor(sc, m, 8);
    if (l == 0) {
      int i = c * NBINS + loc;
      if (i < N_NODES) {
        float val = y[i] + sc / fmaxf((float)(en - st), 1.0f);
        atomicAdd(&gacc[batch[i]], val);
      }
    }
  }
}

// Finalize: out[b] = sigmoid(gacc[b] / |Vb|), |Vb| via binary search.
__global__ __launch_bounds__(256) void k_pool(
    const int* __restrict__ batch, const float* __restrict__ gacc,
    float* __restrict__ out)
{
  int b = blockIdx.x * 256 + (int)threadIdx.x;
  if (b >= B_GRAPHS) return;
  int lo = 0, hi = N_NODES;
  while (lo < hi) { int m = (lo + hi) >> 1; if (batch[m] < b) lo = m + 1; else hi = m; }
  int start = lo;
  hi = N_NODES;
  while (lo < hi) { int m = (lo + hi) >> 1; if (batch[m] < b + 1) lo = m + 1; else hi = m; }
  int cnt = lo - start;
  float g = gacc[b] / fmaxf((float)cnt, 1.0f);
  out[b] = 1.0f / (1.0f + expf(-g));
}

extern "C" void kernel_launch(void* const* d_in, const int* in_sizes, int n_in,
                              void* d_out, int out_size, void* d_ws, size_t ws_size,
                              hipStream_t stream)
{
  const float* x     = (const float*)d_in[0];
  const int*   ei    = (const int*)d_in[1];
  const int*   batch = (const int*)d_in[2];
  const float* W1    = (const float*)d_in[3];
  const float* W2    = (const float*)d_in[4];
  const float* Wfc   = (const float*)d_in[5];
  float* out = (float*)d_out;

  const int* src = ei;            // edge_index[0]
  const int* dst = ei + N_EDGES;  // edge_index[1]

  // ---- workspace layout (u32 element offsets), total ~22.9 MB ----
  u32* wsp = (u32*)d_ws;
  u32* gcurc  = wsp;                                  // 12,512 used (pad 12,544)
  float* gacc = (float*)(wsp + 12544);                // 1000 (pad 1024)
  u32* coarse = wsp + 13568;                          // 782*4608 = 3,603,456
  u32* segg   = coarse + (size_t)NCB * CAPC;          // 782*129 (pad 100,928)
  u32* after  = segg + 100928;
  u16*   q1b = (u16*)after;                           // 800,000 u32
  float* p1  = (float*)(after + 800000);              // 1,000,000 u32
  float* y   = (float*)(after + 1800000);             // 100,096 u32
  float* z   = (float*)(after + 1900096);             // 100,096 u32

  // zero cursors + graph accumulators
  hipMemsetAsync(wsp, 0, 13568 * sizeof(u32), stream);

  k_front<<<NBLK_C + NBLK_N, 256, 0, stream>>>(src, dst, gcurc, coarse,
                                               x, W1, p1, q1b);
  k_lay1<<<NCB, 512, 0, stream>>>(gcurc, coarse, p1, q1b, W2, Wfc, y, z, segg);
  k_lay2<<<NCB, 256, 0, stream>>>(gcurc, coarse, segg, y, z, batch, gacc);
  k_pool<<<4, 256, 0, stream>>>(batch, gacc, out);
}

// Round 11
// 219.166 us; speedup vs baseline: 1.4860x; 1.0705x over previous
//
#include <hip/hip_runtime.h>
#include <cstdint>

typedef unsigned int u32;
typedef unsigned short u16;

#define N_NODES 100000
#define N_EDGES 3200000
#define F_IN 128
#define DIM 10
#define QB 16            // bf16 elems per padded q row -> 32B
#define HPAD 12          // f32 h2 row stride (48B) for the pool kernel
#define B_GRAPHS 1000
#define FRONT_T 512      // threads per k_front block (r11: was 256)
#define NBLK_N 196       // ceil(N/512) gemm blocks

// Front: r4-proven in-LDS chunk sort + coalesced run copy-out, now at 512
// threads/block. Same 42KB LDS -> still 3 blocks/CU, but 24 waves/CU
// (was 12): k_front was latency-bound at 21% occupancy / 1.4 TB/s.
// Back half: byte-identical to r4 (227.5us passing).
#define SHIFTC 7
#define NBINS 128        // dst & 127 within a bucket
#define NCB 782          // ceil(N/128)
#define CAPC 4608        // slots/bucket: mean 4092 + 8 sigma
#define CHUNK_C 8192     // edges per bucketing block
#define NBLK_C 391       // ceil(E/CHUNK_C)
#define GSTRIDE 16       // cursor padding: one 64B line per cursor
#define SEGW 129         // segment-start words per bucket (NBINS+1)

__device__ __forceinline__ u16 f2b(float f) {           // f32 -> bf16 (RNE)
  union { float f; u32 i; } c; c.f = f;
  u32 r = c.i + 0x7FFFu + ((c.i >> 16) & 1u);
  return (u16)(r >> 16);
}
__device__ __forceinline__ float bl(u32 u) {            // low bf16 -> f32
  union { u32 i; float f; } c; c.i = u << 16; return c.f;
}
__device__ __forceinline__ float bh(u32 u) {            // high bf16 -> f32
  union { u32 i; float f; } c; c.i = u & 0xFFFF0000u; return c.f;
}

// ---- gemm1 body: 1 thread/node (512/block), wave-uniform W indexing ----
__device__ __forceinline__ void gemm_body(
    int bid, int tid,
    const float* __restrict__ x, const float* __restrict__ W,
    float* __restrict__ p1, u16* __restrict__ q1b)
{
  int i = bid * FRONT_T + tid;
  if (i >= N_NODES) return;
  const float4* __restrict__ xr = (const float4*)(x + (size_t)i * F_IN);
  float ap[DIM], aq[DIM];
  #pragma unroll
  for (int j = 0; j < DIM; ++j) { ap[j] = 0.f; aq[j] = 0.f; }
  #pragma unroll 4
  for (int k4 = 0; k4 < F_IN / 4; ++k4) {
    float4 v = xr[k4];
    const float* __restrict__ w0 = W + (k4 * 4) * DIM;
    const float* __restrict__ w1 = W + (F_IN + k4 * 4) * DIM;
    #pragma unroll
    for (int j = 0; j < DIM; ++j) {
      ap[j] += v.x * w0[j] + v.y * w0[DIM + j] + v.z * w0[2 * DIM + j] + v.w * w0[3 * DIM + j];
      aq[j] += v.x * w1[j] + v.y * w1[DIM + j] + v.z * w1[2 * DIM + j] + v.w * w1[3 * DIM + j];
    }
  }
  float* pr = p1 + (size_t)i * DIM;
  #pragma unroll
  for (int j = 0; j < DIM; ++j) pr[j] = ap[j];
  u32* qr = (u32*)(q1b + (size_t)i * QB);
  uint4 v0; u32 v1;
  v0.x = (u32)f2b(aq[0]) | ((u32)f2b(aq[1]) << 16);
  v0.y = (u32)f2b(aq[2]) | ((u32)f2b(aq[3]) << 16);
  v0.z = (u32)f2b(aq[4]) | ((u32)f2b(aq[5]) << 16);
  v0.w = (u32)f2b(aq[6]) | ((u32)f2b(aq[7]) << 16);
  v1   = (u32)f2b(aq[8]) | ((u32)f2b(aq[9]) << 16);
  *(uint4*)qr = v0;
  qr[4] = v1;
}

// ---- bucketing body: partition edges into 782 ranges (128 dst each) ----
// Record: ((dst & 127) << 17) | src   (src < 2^17)
// In-LDS counting sort by bucket id, then coalesced run-copy to global.
// 512 threads: 4 iters x 2048 edges; scan section guarded to tid<256.
__device__ __forceinline__ void coarse_body(
    int bid, int tid,
    const int* __restrict__ src, const int* __restrict__ dst,
    u32* __restrict__ gcurc, u32* __restrict__ coarse)
{
  __shared__ u32 srt[CHUNK_C];        // 32 KB: chunk sorted by bucket id
  __shared__ u32 segst[NCB + 1];      // 3.1 KB: local exclusive scan
  __shared__ u32 rank[NCB];           // 3.1 KB: hist, then scatter rank
  __shared__ u32 gbase[NCB];          // 3.1 KB: global base per bucket
  __shared__ u32 wtot[4];

  for (int t = tid; t < NCB; t += FRONT_T) rank[t] = 0u;
  __syncthreads();

  int base = bid * CHUNK_C;
  const int4* __restrict__ dst4 = (const int4*)dst;
  const int4* __restrict__ src4 = (const int4*)src;
  // pass 1: histogram (int4 loads: 4 edges/thread/iter, 4 indep atomics)
  #pragma unroll
  for (int it = 0; it < CHUNK_C / (FRONT_T * 4); ++it) {
    int e = base + it * (FRONT_T * 4) + tid * 4;
    if (e < N_EDGES) {     // N_EDGES % 4 == 0, e % 4 == 0 -> whole int4 ok
      int4 d = dst4[(base >> 2) + it * FRONT_T + tid];
      atomicAdd(&rank[(u32)d.x >> SHIFTC], 1u);
      atomicAdd(&rank[(u32)d.y >> SHIFTC], 1u);
      atomicAdd(&rank[(u32)d.z >> SHIFTC], 1u);
      atomicAdd(&rank[(u32)d.w >> SHIFTC], 1u);
    }
  }
  __syncthreads();

  // exclusive scan of 782 bins: threads 0..195 hold 4 bins each; the wave
  // scan runs on waves 0..3 only (tid<256 guard -> wtot[4] stays in range).
  if (tid < 256) {
    u32 lh[4] = {0u, 0u, 0u, 0u};
    u32 lsum = 0u;
    if (tid < 196) {
      #pragma unroll
      for (int k = 0; k < 4; ++k) {
        int b4 = tid * 4 + k;
        lh[k] = (b4 < NCB) ? rank[b4] : 0u;
        lsum += lh[k];
      }
    }
    u32 v = lsum;
    #pragma unroll
    for (int off = 1; off < 64; off <<= 1) {
      u32 t = __shfl_up(v, off, 64);
      if ((tid & 63) >= off) v += t;
    }
    if ((tid & 63) == 63) wtot[tid >> 6] = v;
    __syncthreads();
    u32 wofs = 0u;
    #pragma unroll
    for (int w = 0; w < 3; ++w) if ((tid >> 6) > w) wofs += wtot[w];
    if (tid < 196) {
      u32 excl = wofs + v - lsum;    // exclusive prefix across threads
      #pragma unroll
      for (int k = 0; k < 4; ++k) {
        int b4 = tid * 4 + k;
        if (b4 < NCB) segst[b4] = excl;
        excl += lh[k];
      }
      if (tid == 195) segst[NCB] = excl;   // chunk total
    }
  } else {
    __syncthreads();                 // match the barrier inside the guard
  }
  __syncthreads();

  // reserve global space per bucket; reset rank for the scatter pass
  for (int t = tid; t < NCB; t += FRONT_T) {
    u32 c = segst[t + 1] - segst[t];
    gbase[t] = c ? atomicAdd(&gcurc[t * GSTRIDE], c) : 0u;
    rank[t] = 0u;
  }
  __syncthreads();

  // pass 2: scatter into LDS (sorted by bucket id)
  #pragma unroll
  for (int it = 0; it < CHUNK_C / (FRONT_T * 4); ++it) {
    int e = base + it * (FRONT_T * 4) + tid * 4;
    if (e < N_EDGES) {
      int4 d = dst4[(base >> 2) + it * FRONT_T + tid];
      int4 s = src4[(base >> 2) + it * FRONT_T + tid];
      #pragma unroll
      for (int q = 0; q < 4; ++q) {
        u32 dd = (u32)((q == 0) ? d.x : (q == 1) ? d.y : (q == 2) ? d.z : d.w);
        u32 ss = (u32)((q == 0) ? s.x : (q == 1) ? s.y : (q == 2) ? s.z : s.w);
        u32 cb = dd >> SHIFTC;
        u32 pos = segst[cb] + atomicAdd(&rank[cb], 1u);
        srt[pos] = ((dd & (NBINS - 1u)) << 17) | ss;   // pos < CHUNK_C always
      }
    }
  }
  __syncthreads();

  // phase W: 16-lane groups copy per-bucket runs (contiguous -> coalesced)
  int grp = tid >> 4, lane = tid & 15;          // 32 groups
  for (int cb = grp; cb < NCB; cb += FRONT_T / 16) {
    u32 st = segst[cb];
    u32 cnt = segst[cb + 1] - st;
    u32 gb = gbase[cb];
    for (u32 r = lane; r < cnt; r += 16u) {
      u32 p = gb + r;
      if (p < CAPC)     // statistically impossible; memory-safety only
        coarse[(size_t)cb * CAPC + p] = srt[st + r];
    }
  }
}

// Fused front: blocks [0,NBLK_C) bucket edges, [NBLK_C,+NBLK_N) run gemm1.
__global__ __launch_bounds__(FRONT_T) void k_front(
    const int* __restrict__ src, const int* __restrict__ dst,
    u32* __restrict__ gcurc, u32* __restrict__ coarse,
    const float* __restrict__ x, const float* __restrict__ W,
    float* __restrict__ p1, u16* __restrict__ q1b)
{
  if (blockIdx.x < NBLK_C)
    coarse_body(blockIdx.x, threadIdx.x, src, dst, gcurc, coarse);
  else
    gemm_body(blockIdx.x - NBLK_C, threadIdx.x, x, W, p1, q1b);
}

// Segment gather: assumes srt (LDS sorted src), st, en, l in scope.
// Produces s[DIM] = 8-lane-reduced partial sums.
#define SEG_GATHER(QSRC)                                                      \
  float s[DIM];                                                               \
  _Pragma("unroll")                                                           \
  for (int j = 0; j < DIM; ++j) s[j] = 0.f;                                   \
  {                                                                           \
    int k = st + l;                                                           \
    for (; k + 8 < en; k += 16) {                                             \
      int s0 = (int)srt[k], s1 = (int)srt[k + 8];                             \
      const u32* __restrict__ q0 = (const u32*)(QSRC + (size_t)s0 * QB);      \
      const u32* __restrict__ q1 = (const u32*)(QSRC + (size_t)s1 * QB);      \
      uint4 A0 = *(const uint4*)q0; u32 B0 = q0[4];                           \
      uint4 A1 = *(const uint4*)q1; u32 B1 = q1[4];                           \
      s[0] += bl(A0.x) + bl(A1.x); s[1] += bh(A0.x) + bh(A1.x);               \
      s[2] += bl(A0.y) + bl(A1.y); s[3] += bh(A0.y) + bh(A1.y);               \
      s[4] += bl(A0.z) + bl(A1.z); s[5] += bh(A0.z) + bh(A1.z);               \
      s[6] += bl(A0.w) + bl(A1.w); s[7] += bh(A0.w) + bh(A1.w);               \
      s[8] += bl(B0) + bl(B1);     s[9] += bh(B0) + bh(B1);                   \
    }                                                                         \
    if (k < en) {                                                             \
      int s0 = (int)srt[k];                                                   \
      const u32* __restrict__ q0 = (const u32*)(QSRC + (size_t)s0 * QB);      \
      uint4 A0 = *(const uint4*)q0; u32 B0 = q0[4];                           \
      s[0] += bl(A0.x); s[1] += bh(A0.x);                                     \
      s[2] += bl(A0.y); s[3] += bh(A0.y);                                     \
      s[4] += bl(A0.z); s[5] += bh(A0.z);                                     \
      s[6] += bl(A0.w); s[7] += bh(A0.w);                                     \
      s[8] += bl(B0);   s[9] += bh(B0);                                       \
    }                                                                         \
  }                                                                           \
  _Pragma("unroll")                                                           \
  for (int m = 1; m < 8; m <<= 1) {                                           \
    _Pragma("unroll")                                                         \
    for (int j = 0; j < DIM; ++j) s[j] += __shfl_xor(s[j], m, 8);             \
  }

// Layer 1: counting-sort a whole 128-dst bucket (~4092 records) in LDS,
// PERSIST the sorted order (coarse in place + segment table) for k_lay2,
// gather, epilogue h = relu(p1+mean), (p2,q2) = h @ W2.
__global__ __launch_bounds__(512) void k_lay1(
    const u32* __restrict__ gcurc, u32* __restrict__ coarse,
    const float* __restrict__ p1, const u16* __restrict__ q1b,
    const float* __restrict__ W2,
    float* __restrict__ p2, u16* __restrict__ q2b,
    u32* __restrict__ segg)
{
  __shared__ u32 lrec[CAPC];          // 18 KB
  __shared__ u32 srt[CAPC];           // 18 KB
  __shared__ u32 hist[NBINS];
  __shared__ u32 segst[NBINS + 1];
  __shared__ u32 rank[NBINS];
  __shared__ u32 wtot[2];
  __shared__ float w[2 * DIM * DIM];
  int tid = threadIdx.x;
  int c = blockIdx.x;
  for (int t = tid; t < 2 * DIM * DIM; t += 512) w[t] = W2[t];
  if (tid < NBINS) { hist[tid] = 0u; rank[tid] = 0u; }
  __syncthreads();
  int n = min((int)gcurc[c * GSTRIDE], CAPC);
  const u32* __restrict__ rc = coarse + (size_t)c * CAPC;
  for (int r = tid; r < n; r += 512) {
    u32 v = rc[r];
    lrec[r] = v;
    atomicAdd(&hist[(v >> 17) & (NBINS - 1u)], 1u);
  }
  __syncthreads();
  // 128-bin exclusive scan: intra-wave shfl scan + cross-wave offset
  if (tid < NBINS) {
    u32 h = hist[tid];
    u32 v = h;
    #pragma unroll
    for (int off = 1; off < 64; off <<= 1) {
      u32 t = __shfl_up(v, off, 64);
      if ((tid & 63) >= off) v += t;
    }
    if ((tid & 63) == 63) wtot[tid >> 6] = v;
    segst[tid] = v - h;
  }
  __syncthreads();
  if (tid >= 64 && tid < NBINS) segst[tid] += wtot[0];
  if (tid == 0) segst[NBINS] = wtot[0] + wtot[1];
  __syncthreads();
  for (int r = tid; r < n; r += 512) {
    u32 v = lrec[r];
    u32 dl = (v >> 17) & (NBINS - 1u);
    u32 pos = segst[dl] + atomicAdd(&rank[dl], 1u);
    srt[pos] = v & 0x1FFFFu;
  }
  __syncthreads();
  // persist sorted order (k_lay2 skips the whole sort)
  for (int r = tid; r < n; r += 512) coarse[(size_t)c * CAPC + r] = srt[r];
  if (tid <= NBINS) segg[(size_t)c * SEGW + tid] = segst[tid];
  // gather + epilogue: 64 groups of 8 lanes, 2 rounds cover 128 nodes
  int g0 = tid >> 3, l = tid & 7;
  #pragma unroll
  for (int rd = 0; rd < 2; ++rd) {
    int g2 = rd * 64 + g0;
    int st = (int)segst[g2], en = (int)segst[g2 + 1];
    SEG_GATHER(q1b)
    if (l == 0) {
      int i = c * NBINS + g2;
      if (i < N_NODES) {
        float inv = 1.0f / fmaxf((float)(en - st), 1.0f);
        const float* __restrict__ pr = p1 + (size_t)i * DIM;
        float h[DIM];
        #pragma unroll
        for (int j = 0; j < DIM; ++j) h[j] = fmaxf(pr[j] + s[j] * inv, 0.0f);
        float aa[DIM], bb[DIM];
        #pragma unroll
        for (int j = 0; j < DIM; ++j) {
          float t0 = 0.f, t1 = 0.f;
          #pragma unroll
          for (int kk = 0; kk < DIM; ++kk) {
            t0 += h[kk] * w[kk * DIM + j];
            t1 += h[kk] * w[(DIM + kk) * DIM + j];
          }
          aa[j] = t0; bb[j] = t1;
        }
        float* po = p2 + (size_t)i * DIM;
        #pragma unroll
        for (int j = 0; j < DIM; ++j) po[j] = aa[j];
        u32* qo = (u32*)(q2b + (size_t)i * QB);
        uint4 v0; u32 v1;
        v0.x = (u32)f2b(bb[0]) | ((u32)f2b(bb[1]) << 16);
        v0.y = (u32)f2b(bb[2]) | ((u32)f2b(bb[3]) << 16);
        v0.z = (u32)f2b(bb[4]) | ((u32)f2b(bb[5]) << 16);
        v0.w = (u32)f2b(bb[6]) | ((u32)f2b(bb[7]) << 16);
        v1   = (u32)f2b(bb[8]) | ((u32)f2b(bb[9]) << 16);
        *(uint4*)qo = v0;
        qo[4] = v1;
      }
    }
  }
}

// Layer 2: NO sort — stage the already-sorted records + segment table,
// gather, epilogue h2 = p2 + mean (f32, stride 12).
__global__ __launch_bounds__(512) void k_lay2(
    const u32* __restrict__ gcurc, const u32* __restrict__ coarse,
    const u32* __restrict__ segg,
    const float* __restrict__ p2, const u16* __restrict__ q2b,
    float* __restrict__ h2)
{
  __shared__ u32 srt[CAPC];           // 18 KB
  __shared__ u32 segst[NBINS + 1];
  int tid = threadIdx.x;
  int c = blockIdx.x;
  if (tid <= NBINS) segst[tid] = segg[(size_t)c * SEGW + tid];
  int n = min((int)gcurc[c * GSTRIDE], CAPC);
  const u32* __restrict__ rc = coarse + (size_t)c * CAPC;
  for (int r = tid; r < n; r += 512) srt[r] = rc[r];
  __syncthreads();
  int g0 = tid >> 3, l = tid & 7;
  #pragma unroll
  for (int rd = 0; rd < 2; ++rd) {
    int g2 = rd * 64 + g0;
    int st = (int)segst[g2], en = (int)segst[g2 + 1];
    SEG_GATHER(q2b)
    if (l == 0) {
      int i = c * NBINS + g2;
      if (i < N_NODES) {
        float inv = 1.0f / fmaxf((float)(en - st), 1.0f);
        const float* __restrict__ pr = p2 + (size_t)i * DIM;
        float* ho = h2 + (size_t)i * HPAD;
        #pragma unroll
        for (int j = 0; j < DIM; ++j) ho[j] = pr[j] + s[j] * inv;
      }
    }
  }
}

// one wave per graph: binary-search node range in sorted batch, mean-pool,
// dot with Wfc, sigmoid -> out[b]. Zero atomics.
__global__ __launch_bounds__(64) void k_pool(
    const float* __restrict__ h2, const int* __restrict__ batch,
    const float* __restrict__ Wfc, float* __restrict__ out)
{
  int b = blockIdx.x;
  int lo = 0, hi = N_NODES;
  while (lo < hi) { int m = (lo + hi) >> 1; if (batch[m] < b) lo = m + 1; else hi = m; }
  int start = lo;
  hi = N_NODES;
  while (lo < hi) { int m = (lo + hi) >> 1; if (batch[m] < b + 1) lo = m + 1; else hi = m; }
  int end = lo;
  float sum[DIM];
  #pragma unroll
  for (int j = 0; j < DIM; ++j) sum[j] = 0.f;
  for (int r = start + (int)threadIdx.x; r < end; r += 64) {
    const float4* __restrict__ p = (const float4*)(h2 + (size_t)r * HPAD);
    float4 r0 = p[0], r1 = p[1];
    float2 r2 = *(const float2*)(h2 + (size_t)r * HPAD + 8);
    sum[0] += r0.x; sum[1] += r0.y; sum[2] += r0.z; sum[3] += r0.w;
    sum[4] += r1.x; sum[5] += r1.y; sum[6] += r1.z; sum[7] += r1.w;
    sum[8] += r2.x; sum[9] += r2.y;
  }
  #pragma unroll
  for (int m = 1; m < 64; m <<= 1) {
    #pragma unroll
    for (int j = 0; j < DIM; ++j) sum[j] += __shfl_xor(sum[j], m, 64);
  }
  if (threadIdx.x == 0) {
    float inv = 1.0f / fmaxf((float)(end - start), 1.0f);
    float acc = 0.f;
    #pragma unroll
    for (int j = 0; j < DIM; ++j) acc += sum[j] * inv * Wfc[j];
    out[b] = 1.0f / (1.0f + expf(-acc));
  }
}

extern "C" void kernel_launch(void* const* d_in, const int* in_sizes, int n_in,
                              void* d_out, int out_size, void* d_ws, size_t ws_size,
                              hipStream_t stream)
{
  const float* x     = (const float*)d_in[0];
  const int*   ei    = (const int*)d_in[1];
  const int*   batch = (const int*)d_in[2];
  const float* W1    = (const float*)d_in[3];
  const float* W2    = (const float*)d_in[4];
  const float* Wfc   = (const float*)d_in[5];
  float* out = (float*)d_out;

  const int* src = ei;            // edge_index[0]
  const int* dst = ei + N_EDGES;  // edge_index[1]

  // ---- workspace layout (u32 element offsets), total ~34.1 MB ----
  u32* wsp = (u32*)d_ws;
  u32* gcurc  = wsp;                                  // 12,512 used (pad 12,544)
  u32* coarse = wsp + 12544;                          // 782*4608 = 3,603,456
  u32* segg   = coarse + (size_t)NCB * CAPC;          // 782*129 (pad 100,928)
  u32* after  = segg + 100928;
  u16*   q1b = (u16*)after;                           // 800,000 u32
  float* p1  = (float*)(after + 800000);              // 1,000,000 u32
  u16*   q2b = (u16*)(after + 1800000);               // 800,000 u32
  float* p2  = (float*)(after + 2600000);             // 1,000,000 u32
  float* h2  = (float*)(after + 3600000);             // 1,200,000 u32

  hipMemsetAsync(gcurc, 0, (size_t)NCB * GSTRIDE * sizeof(u32), stream);

  k_front<<<NBLK_C + NBLK_N, FRONT_T, 0, stream>>>(src, dst, gcurc, coarse,
                                                   x, W1, p1, q1b);
  k_lay1<<<NCB, 512, 0, stream>>>(gcurc, coarse, p1, q1b, W2, p2, q2b, segg);
  k_lay2<<<NCB, 512, 0, stream>>>(gcurc, coarse, segg, p2, q2b, h2);
  k_pool<<<B_GRAPHS, 64, 0, stream>>>(h2, batch, Wfc, out);
}

// Round 12
// 195.098 us; speedup vs baseline: 1.6693x; 1.1234x over previous
//
#include <hip/hip_runtime.h>
#include <cstdint>

typedef unsigned int u32;
typedef unsigned short u16;

#define N_NODES 100000
#define N_EDGES 3200000
#define F_IN 128
#define DIM 10
#define QB 16            // bf16 elems per padded q row -> 32B
#define B_GRAPHS 1000
#define FRONT_T 512      // threads per k_front block (r11-proven)
#define NBLK_N 196       // ceil(N/512) gemm blocks

// Front: r11-proven (512-thr in-LDS chunk sort + coalesced run copy-out).
// Back half (r12): r7's linear collapse (y=h.wv1, z=h.wv2) + lay2+pool
// MERGED into per-graph k_zpool (streams persisted sorted records via
// segg, gathers 4B z[src] from L2-resident table, zero atomics).
// Deletes: p2/q2b (7.2MB), h2 (4.8MB), lay2's 12.8MB LDS restage, one
// dispatch+drain.
#define SHIFTC 7
#define NBINS 128        // dst & 127 within a bucket
#define NCB 782          // ceil(N/128)
#define CAPC 4608        // slots/bucket: mean 4092 + 8 sigma
#define CHUNK_C 8192     // edges per bucketing block
#define NBLK_C 391       // ceil(E/CHUNK_C)
#define GSTRIDE 16       // cursor padding: one 64B line per cursor
#define SEGW 129         // segment-start words per bucket (NBINS+1)

__device__ __forceinline__ u16 f2b(float f) {           // f32 -> bf16 (RNE)
  union { float f; u32 i; } c; c.f = f;
  u32 r = c.i + 0x7FFFu + ((c.i >> 16) & 1u);
  return (u16)(r >> 16);
}
__device__ __forceinline__ float bl(u32 u) {            // low bf16 -> f32
  union { u32 i; float f; } c; c.i = u << 16; return c.f;
}
__device__ __forceinline__ float bh(u32 u) {            // high bf16 -> f32
  union { u32 i; float f; } c; c.i = u & 0xFFFF0000u; return c.f;
}

// ---- gemm1 body: 1 thread/node (512/block), wave-uniform W indexing ----
__device__ __forceinline__ void gemm_body(
    int bid, int tid,
    const float* __restrict__ x, const float* __restrict__ W,
    float* __restrict__ p1, u16* __restrict__ q1b)
{
  int i = bid * FRONT_T + tid;
  if (i >= N_NODES) return;
  const float4* __restrict__ xr = (const float4*)(x + (size_t)i * F_IN);
  float ap[DIM], aq[DIM];
  #pragma unroll
  for (int j = 0; j < DIM; ++j) { ap[j] = 0.f; aq[j] = 0.f; }
  #pragma unroll 4
  for (int k4 = 0; k4 < F_IN / 4; ++k4) {
    float4 v = xr[k4];
    const float* __restrict__ w0 = W + (k4 * 4) * DIM;
    const float* __restrict__ w1 = W + (F_IN + k4 * 4) * DIM;
    #pragma unroll
    for (int j = 0; j < DIM; ++j) {
      ap[j] += v.x * w0[j] + v.y * w0[DIM + j] + v.z * w0[2 * DIM + j] + v.w * w0[3 * DIM + j];
      aq[j] += v.x * w1[j] + v.y * w1[DIM + j] + v.z * w1[2 * DIM + j] + v.w * w1[3 * DIM + j];
    }
  }
  float* pr = p1 + (size_t)i * DIM;
  #pragma unroll
  for (int j = 0; j < DIM; ++j) pr[j] = ap[j];
  u32* qr = (u32*)(q1b + (size_t)i * QB);
  uint4 v0; u32 v1;
  v0.x = (u32)f2b(aq[0]) | ((u32)f2b(aq[1]) << 16);
  v0.y = (u32)f2b(aq[2]) | ((u32)f2b(aq[3]) << 16);
  v0.z = (u32)f2b(aq[4]) | ((u32)f2b(aq[5]) << 16);
  v0.w = (u32)f2b(aq[6]) | ((u32)f2b(aq[7]) << 16);
  v1   = (u32)f2b(aq[8]) | ((u32)f2b(aq[9]) << 16);
  *(uint4*)qr = v0;
  qr[4] = v1;
}

// ---- bucketing body: partition edges into 782 ranges (128 dst each) ----
// Record: ((dst & 127) << 17) | src   (src < 2^17)
// In-LDS counting sort by bucket id, then coalesced run-copy to global.
// 512 threads: 4 iters x 2048 edges; scan section guarded to tid<256.
__device__ __forceinline__ void coarse_body(
    int bid, int tid,
    const int* __restrict__ src, const int* __restrict__ dst,
    u32* __restrict__ gcurc, u32* __restrict__ coarse)
{
  __shared__ u32 srt[CHUNK_C];        // 32 KB: chunk sorted by bucket id
  __shared__ u32 segst[NCB + 1];      // 3.1 KB: local exclusive scan
  __shared__ u32 rank[NCB];           // 3.1 KB: hist, then scatter rank
  __shared__ u32 gbase[NCB];          // 3.1 KB: global base per bucket
  __shared__ u32 wtot[4];

  for (int t = tid; t < NCB; t += FRONT_T) rank[t] = 0u;
  __syncthreads();

  int base = bid * CHUNK_C;
  const int4* __restrict__ dst4 = (const int4*)dst;
  const int4* __restrict__ src4 = (const int4*)src;
  // pass 1: histogram (int4 loads: 4 edges/thread/iter, 4 indep atomics)
  #pragma unroll
  for (int it = 0; it < CHUNK_C / (FRONT_T * 4); ++it) {
    int e = base + it * (FRONT_T * 4) + tid * 4;
    if (e < N_EDGES) {     // N_EDGES % 4 == 0, e % 4 == 0 -> whole int4 ok
      int4 d = dst4[(base >> 2) + it * FRONT_T + tid];
      atomicAdd(&rank[(u32)d.x >> SHIFTC], 1u);
      atomicAdd(&rank[(u32)d.y >> SHIFTC], 1u);
      atomicAdd(&rank[(u32)d.z >> SHIFTC], 1u);
      atomicAdd(&rank[(u32)d.w >> SHIFTC], 1u);
    }
  }
  __syncthreads();

  // exclusive scan of 782 bins: threads 0..195 hold 4 bins each; the wave
  // scan runs on waves 0..3 only (tid<256 guard -> wtot[4] stays in range).
  if (tid < 256) {
    u32 lh[4] = {0u, 0u, 0u, 0u};
    u32 lsum = 0u;
    if (tid < 196) {
      #pragma unroll
      for (int k = 0; k < 4; ++k) {
        int b4 = tid * 4 + k;
        lh[k] = (b4 < NCB) ? rank[b4] : 0u;
        lsum += lh[k];
      }
    }
    u32 v = lsum;
    #pragma unroll
    for (int off = 1; off < 64; off <<= 1) {
      u32 t = __shfl_up(v, off, 64);
      if ((tid & 63) >= off) v += t;
    }
    if ((tid & 63) == 63) wtot[tid >> 6] = v;
    __syncthreads();
    u32 wofs = 0u;
    #pragma unroll
    for (int w = 0; w < 3; ++w) if ((tid >> 6) > w) wofs += wtot[w];
    if (tid < 196) {
      u32 excl = wofs + v - lsum;    // exclusive prefix across threads
      #pragma unroll
      for (int k = 0; k < 4; ++k) {
        int b4 = tid * 4 + k;
        if (b4 < NCB) segst[b4] = excl;
        excl += lh[k];
      }
      if (tid == 195) segst[NCB] = excl;   // chunk total
    }
  } else {
    __syncthreads();                 // match the barrier inside the guard
  }
  __syncthreads();

  // reserve global space per bucket; reset rank for the scatter pass
  for (int t = tid; t < NCB; t += FRONT_T) {
    u32 c = segst[t + 1] - segst[t];
    gbase[t] = c ? atomicAdd(&gcurc[t * GSTRIDE], c) : 0u;
    rank[t] = 0u;
  }
  __syncthreads();

  // pass 2: scatter into LDS (sorted by bucket id)
  #pragma unroll
  for (int it = 0; it < CHUNK_C / (FRONT_T * 4); ++it) {
    int e = base + it * (FRONT_T * 4) + tid * 4;
    if (e < N_EDGES) {
      int4 d = dst4[(base >> 2) + it * FRONT_T + tid];
      int4 s = src4[(base >> 2) + it * FRONT_T + tid];
      #pragma unroll
      for (int q = 0; q < 4; ++q) {
        u32 dd = (u32)((q == 0) ? d.x : (q == 1) ? d.y : (q == 2) ? d.z : d.w);
        u32 ss = (u32)((q == 0) ? s.x : (q == 1) ? s.y : (q == 2) ? s.z : s.w);
        u32 cb = dd >> SHIFTC;
        u32 pos = segst[cb] + atomicAdd(&rank[cb], 1u);
        srt[pos] = ((dd & (NBINS - 1u)) << 17) | ss;   // pos < CHUNK_C always
      }
    }
  }
  __syncthreads();

  // phase W: 16-lane groups copy per-bucket runs (contiguous -> coalesced)
  int grp = tid >> 4, lane = tid & 15;          // 32 groups
  for (int cb = grp; cb < NCB; cb += FRONT_T / 16) {
    u32 st = segst[cb];
    u32 cnt = segst[cb + 1] - st;
    u32 gb = gbase[cb];
    for (u32 r = lane; r < cnt; r += 16u) {
      u32 p = gb + r;
      if (p < CAPC)     // statistically impossible; memory-safety only
        coarse[(size_t)cb * CAPC + p] = srt[st + r];
    }
  }
}

// Fused front: blocks [0,NBLK_C) bucket edges, [NBLK_C,+NBLK_N) run gemm1.
__global__ __launch_bounds__(FRONT_T) void k_front(
    const int* __restrict__ src, const int* __restrict__ dst,
    u32* __restrict__ gcurc, u32* __restrict__ coarse,
    const float* __restrict__ x, const float* __restrict__ W,
    float* __restrict__ p1, u16* __restrict__ q1b)
{
  if (blockIdx.x < NBLK_C)
    coarse_body(blockIdx.x, threadIdx.x, src, dst, gcurc, coarse);
  else
    gemm_body(blockIdx.x - NBLK_C, threadIdx.x, x, W, p1, q1b);
}

// Segment gather: assumes srt (LDS sorted src), st, en, l in scope.
// Produces s[DIM] = 8-lane-reduced partial sums.
#define SEG_GATHER(QSRC)                                                      \
  float s[DIM];                                                               \
  _Pragma("unroll")                                                           \
  for (int j = 0; j < DIM; ++j) s[j] = 0.f;                                   \
  {                                                                           \
    int k = st + l;                                                           \
    for (; k + 8 < en; k += 16) {                                             \
      int s0 = (int)srt[k], s1 = (int)srt[k + 8];                             \
      const u32* __restrict__ q0 = (const u32*)(QSRC + (size_t)s0 * QB);      \
      const u32* __restrict__ q1 = (const u32*)(QSRC + (size_t)s1 * QB);      \
      uint4 A0 = *(const uint4*)q0; u32 B0 = q0[4];                           \
      uint4 A1 = *(const uint4*)q1; u32 B1 = q1[4];                           \
      s[0] += bl(A0.x) + bl(A1.x); s[1] += bh(A0.x) + bh(A1.x);               \
      s[2] += bl(A0.y) + bl(A1.y); s[3] += bh(A0.y) + bh(A1.y);               \
      s[4] += bl(A0.z) + bl(A1.z); s[5] += bh(A0.z) + bh(A1.z);               \
      s[6] += bl(A0.w) + bl(A1.w); s[7] += bh(A0.w) + bh(A1.w);               \
      s[8] += bl(B0) + bl(B1);     s[9] += bh(B0) + bh(B1);                   \
    }                                                                         \
    if (k < en) {                                                             \
      int s0 = (int)srt[k];                                                   \
      const u32* __restrict__ q0 = (const u32*)(QSRC + (size_t)s0 * QB);      \
      uint4 A0 = *(const uint4*)q0; u32 B0 = q0[4];                           \
      s[0] += bl(A0.x); s[1] += bh(A0.x);                                     \
      s[2] += bl(A0.y); s[3] += bh(A0.y);                                     \
      s[4] += bl(A0.z); s[5] += bh(A0.z);                                     \
      s[6] += bl(A0.w); s[7] += bh(A0.w);                                     \
      s[8] += bl(B0);   s[9] += bh(B0);                                       \
    }                                                                         \
  }                                                                           \
  _Pragma("unroll")                                                           \
  for (int m = 1; m < 8; m <<= 1) {                                           \
    _Pragma("unroll")                                                         \
    for (int j = 0; j < DIM; ++j) s[j] += __shfl_xor(s[j], m, 8);             \
  }

// Layer 1: counting-sort a whole 128-dst bucket (~4092 records) in LDS,
// PERSIST the sorted order (coarse in place + segg) for k_zpool, gather,
// epilogue h = relu(p1+mean); y = h.wv1, z = h.wv2 (folded W2@Wfc, r7).
__global__ __launch_bounds__(512) void k_lay1(
    const u32* __restrict__ gcurc, u32* __restrict__ coarse,
    const float* __restrict__ p1, const u16* __restrict__ q1b,
    const float* __restrict__ W2, const float* __restrict__ Wfc,
    float* __restrict__ y, float* __restrict__ z,
    u32* __restrict__ segg)
{
  __shared__ u32 lrec[CAPC];          // 18 KB
  __shared__ u32 srt[CAPC];           // 18 KB
  __shared__ u32 hist[NBINS];
  __shared__ u32 segst[NBINS + 1];
  __shared__ u32 rank[NBINS];
  __shared__ u32 wtot[2];
  __shared__ float wv[2 * DIM];       // wv[k] = sum_j W2[k][j] * Wfc[j]
  int tid = threadIdx.x;
  int c = blockIdx.x;
  if (tid < 2 * DIM) {
    float sacc = 0.f;
    #pragma unroll
    for (int j = 0; j < DIM; ++j) sacc += W2[tid * DIM + j] * Wfc[j];
    wv[tid] = sacc;
  }
  if (tid < NBINS) { hist[tid] = 0u; rank[tid] = 0u; }
  __syncthreads();
  int n = min((int)gcurc[c * GSTRIDE], CAPC);
  const u32* __restrict__ rc = coarse + (size_t)c * CAPC;
  for (int r = tid; r < n; r += 512) {
    u32 v = rc[r];
    lrec[r] = v;
    atomicAdd(&hist[(v >> 17) & (NBINS - 1u)], 1u);
  }
  __syncthreads();
  // 128-bin exclusive scan: intra-wave shfl scan + cross-wave offset
  if (tid < NBINS) {
    u32 h = hist[tid];
    u32 v = h;
    #pragma unroll
    for (int off = 1; off < 64; off <<= 1) {
      u32 t = __shfl_up(v, off, 64);
      if ((tid & 63) >= off) v += t;
    }
    if ((tid & 63) == 63) wtot[tid >> 6] = v;
    segst[tid] = v - h;
  }
  __syncthreads();
  if (tid >= 64 && tid < NBINS) segst[tid] += wtot[0];
  if (tid == 0) segst[NBINS] = wtot[0] + wtot[1];
  __syncthreads();
  for (int r = tid; r < n; r += 512) {
    u32 v = lrec[r];
    u32 dl = (v >> 17) & (NBINS - 1u);
    u32 pos = segst[dl] + atomicAdd(&rank[dl], 1u);
    srt[pos] = v & 0x1FFFFu;
  }
  __syncthreads();
  // persist sorted order + segment table (k_zpool streams them)
  for (int r = tid; r < n; r += 512) coarse[(size_t)c * CAPC + r] = srt[r];
  if (tid <= NBINS) segg[(size_t)c * SEGW + tid] = segst[tid];
  // gather + epilogue: 64 groups of 8 lanes, 2 rounds cover 128 nodes
  int g0 = tid >> 3, l = tid & 7;
  #pragma unroll
  for (int rd = 0; rd < 2; ++rd) {
    int g2 = rd * 64 + g0;
    int st = (int)segst[g2], en = (int)segst[g2 + 1];
    SEG_GATHER(q1b)
    if (l == 0) {
      int i = c * NBINS + g2;
      if (i < N_NODES) {
        float dinv = 1.0f / fmaxf((float)(en - st), 1.0f);
        const float* __restrict__ pr = p1 + (size_t)i * DIM;
        float yv = 0.f, zv = 0.f;
        #pragma unroll
        for (int j = 0; j < DIM; ++j) {
          float h = fmaxf(pr[j] + s[j] * dinv, 0.0f);
          yv += h * wv[j];
          zv += h * wv[DIM + j];
        }
        y[i] = yv;
        z[i] = zv;
      }
    }
  }
}

// Merged layer2+pool: one block per graph. For each node in the graph's
// contiguous range, stream its persisted sorted segment (segg lookup),
// gather z[src] (4B, L2-resident 400KB table), val = y + mean(z-seg);
// block-reduce, sigmoid -> out[g]. Zero atomics, no h2, no LDS staging.
__global__ __launch_bounds__(256) void k_zpool(
    const u32* __restrict__ coarse, const u32* __restrict__ segg,
    const float* __restrict__ y, const float* __restrict__ z,
    const int* __restrict__ batch, float* __restrict__ out)
{
  __shared__ float wsum[4];
  int g = blockIdx.x;
  int tid = threadIdx.x;
  int lo = 0, hi = N_NODES;
  while (lo < hi) { int m = (lo + hi) >> 1; if (batch[m] < g) lo = m + 1; else hi = m; }
  int start = lo;
  hi = N_NODES;
  while (lo < hi) { int m = (lo + hi) >> 1; if (batch[m] < g + 1) lo = m + 1; else hi = m; }
  int end = lo;
  int grp = tid >> 3, l = tid & 7;    // 32 groups of 8 lanes
  float acc = 0.f;
  for (int i = start + grp; i < end; i += 32) {
    int c = i >> SHIFTC, bin = i & (NBINS - 1);
    u32 st = segg[(size_t)c * SEGW + bin];
    u32 en = segg[(size_t)c * SEGW + bin + 1];
    const u32* __restrict__ rc = coarse + (size_t)c * CAPC;
    float sc = 0.f;
    for (u32 k = st + l; k < en; k += 8u) sc += z[rc[k]];
    #pragma unroll
    for (int m = 1; m < 8; m <<= 1) sc += __shfl_xor(sc, m, 8);
    if (l == 0) acc += y[i] + sc / fmaxf((float)(en - st), 1.0f);
  }
  // block reduction (non-l0 lanes hold 0 after masking)
  if (l != 0) acc = 0.f;
  #pragma unroll
  for (int m = 1; m < 64; m <<= 1) acc += __shfl_xor(acc, m, 64);
  if ((tid & 63) == 0) wsum[tid >> 6] = acc;
  __syncthreads();
  if (tid == 0) {
    float tot = wsum[0] + wsum[1] + wsum[2] + wsum[3];
    float gm = tot / fmaxf((float)(end - start), 1.0f);
    out[g] = 1.0f / (1.0f + expf(-gm));
  }
}

extern "C" void kernel_launch(void* const* d_in, const int* in_sizes, int n_in,
                              void* d_out, int out_size, void* d_ws, size_t ws_size,
                              hipStream_t stream)
{
  const float* x     = (const float*)d_in[0];
  const int*   ei    = (const int*)d_in[1];
  const int*   batch = (const int*)d_in[2];
  const float* W1    = (const float*)d_in[3];
  const float* W2    = (const float*)d_in[4];
  const float* Wfc   = (const float*)d_in[5];
  float* out = (float*)d_out;

  const int* src = ei;            // edge_index[0]
  const int* dst = ei + N_EDGES;  // edge_index[1]

  // ---- workspace layout (u32 element offsets), total ~22.9 MB ----
  u32* wsp = (u32*)d_ws;
  u32* gcurc  = wsp;                                  // 12,512 used (pad 12,544)
  u32* coarse = wsp + 12544;                          // 782*4608 = 3,603,456
  u32* segg   = coarse + (size_t)NCB * CAPC;          // 782*129 (pad 100,928)
  u32* after  = segg + 100928;
  u16*   q1b = (u16*)after;                           // 800,000 u32
  float* p1  = (float*)(after + 800000);              // 1,000,000 u32
  float* y   = (float*)(after + 1800000);             // 100,096 u32
  float* z   = (float*)(after + 1900096);             // 100,096 u32

  hipMemsetAsync(gcurc, 0, (size_t)NCB * GSTRIDE * sizeof(u32), stream);

  k_front<<<NBLK_C + NBLK_N, FRONT_T, 0, stream>>>(src, dst, gcurc, coarse,
                                                   x, W1, p1, q1b);
  k_lay1<<<NCB, 512, 0, stream>>>(gcurc, coarse, p1, q1b, W2, Wfc, y, z, segg);
  k_zpool<<<B_GRAPHS, 256, 0, stream>>>(coarse, segg, y, z, batch, out);
}

// Round 13
// 183.010 us; speedup vs baseline: 1.7795x; 1.0661x over previous
//
#include <hip/hip_runtime.h>
#include <cstdint>

typedef unsigned int u32;
typedef unsigned short u16;

#define N_NODES 100000
#define N_EDGES 3200000
#define F_IN 128
#define DIM 10
#define QB 16            // bf16 elems per padded q row -> 32B
#define B_GRAPHS 1000
#define FRONT_T 512      // threads per k_front block (r11-proven)
#define NBLK_N 196       // ceil(N/512) gemm blocks

// r13: STATIC record layout. k_front writes its chunk-sorted records to its
// OWN region rec[bid*CHUNK_C..] (coalesced, amp=1.0) + per-block segment
// table segt[bid][0..782]. No global cursors -> no memset dispatch, no
// cross-XCD reservation atomics. k_lay1 scans the 391 per-block counts and
// gathers bucket c's 391 runs into LDS, then sorts/gathers as in r12.
// k_zpool unchanged from r12 (195.1us passing).
#define SHIFTC 7
#define NBINS 128        // dst & 127 within a bucket
#define NCB 782          // ceil(N/128)
#define CAPC 4608        // slots/bucket: mean 4092 + 8 sigma
#define CHUNK_C 8192     // edges per bucketing block
#define NBLK_C 391       // ceil(E/CHUNK_C)
#define SEGW 129         // segment-start words per bucket (NBINS+1)
#define TW (NCB + 1)     // segt row width (783)

__device__ __forceinline__ u16 f2b(float f) {           // f32 -> bf16 (RNE)
  union { float f; u32 i; } c; c.f = f;
  u32 r = c.i + 0x7FFFu + ((c.i >> 16) & 1u);
  return (u16)(r >> 16);
}
__device__ __forceinline__ float bl(u32 u) {            // low bf16 -> f32
  union { u32 i; float f; } c; c.i = u << 16; return c.f;
}
__device__ __forceinline__ float bh(u32 u) {            // high bf16 -> f32
  union { u32 i; float f; } c; c.i = u & 0xFFFF0000u; return c.f;
}

// ---- gemm1 body: 1 thread/node (512/block), wave-uniform W indexing ----
__device__ __forceinline__ void gemm_body(
    int bid, int tid,
    const float* __restrict__ x, const float* __restrict__ W,
    float* __restrict__ p1, u16* __restrict__ q1b)
{
  int i = bid * FRONT_T + tid;
  if (i >= N_NODES) return;
  const float4* __restrict__ xr = (const float4*)(x + (size_t)i * F_IN);
  float ap[DIM], aq[DIM];
  #pragma unroll
  for (int j = 0; j < DIM; ++j) { ap[j] = 0.f; aq[j] = 0.f; }
  #pragma unroll 4
  for (int k4 = 0; k4 < F_IN / 4; ++k4) {
    float4 v = xr[k4];
    const float* __restrict__ w0 = W + (k4 * 4) * DIM;
    const float* __restrict__ w1 = W + (F_IN + k4 * 4) * DIM;
    #pragma unroll
    for (int j = 0; j < DIM; ++j) {
      ap[j] += v.x * w0[j] + v.y * w0[DIM + j] + v.z * w0[2 * DIM + j] + v.w * w0[3 * DIM + j];
      aq[j] += v.x * w1[j] + v.y * w1[DIM + j] + v.z * w1[2 * DIM + j] + v.w * w1[3 * DIM + j];
    }
  }
  float* pr = p1 + (size_t)i * DIM;
  #pragma unroll
  for (int j = 0; j < DIM; ++j) pr[j] = ap[j];
  u32* qr = (u32*)(q1b + (size_t)i * QB);
  uint4 v0; u32 v1;
  v0.x = (u32)f2b(aq[0]) | ((u32)f2b(aq[1]) << 16);
  v0.y = (u32)f2b(aq[2]) | ((u32)f2b(aq[3]) << 16);
  v0.z = (u32)f2b(aq[4]) | ((u32)f2b(aq[5]) << 16);
  v0.w = (u32)f2b(aq[6]) | ((u32)f2b(aq[7]) << 16);
  v1   = (u32)f2b(aq[8]) | ((u32)f2b(aq[9]) << 16);
  *(uint4*)qr = v0;
  qr[4] = v1;
}

// ---- bucketing body: chunk-sort edges by bucket id (782 buckets), write
// the sorted chunk CONTIGUOUSLY to rec[bid*CHUNK_C..] + segt row.
// Record: ((dst & 127) << 17) | src   (src < 2^17)
__device__ __forceinline__ void coarse_body(
    int bid, int tid,
    const int* __restrict__ src, const int* __restrict__ dst,
    u32* __restrict__ rec, u32* __restrict__ segt)
{
  __shared__ u32 srt[CHUNK_C];        // 32 KB: chunk sorted by bucket id
  __shared__ u32 segst[NCB + 1];      // 3.1 KB: local exclusive scan
  __shared__ u32 rank[NCB];           // 3.1 KB: hist, then scatter rank
  __shared__ u32 wtot[4];

  for (int t = tid; t < NCB; t += FRONT_T) rank[t] = 0u;
  __syncthreads();

  int base = bid * CHUNK_C;
  const int4* __restrict__ dst4 = (const int4*)dst;
  const int4* __restrict__ src4 = (const int4*)src;
  // pass 1: histogram (int4 loads: 4 edges/thread/iter, 4 indep atomics)
  #pragma unroll
  for (int it = 0; it < CHUNK_C / (FRONT_T * 4); ++it) {
    int e = base + it * (FRONT_T * 4) + tid * 4;
    if (e < N_EDGES) {     // N_EDGES % 4 == 0, e % 4 == 0 -> whole int4 ok
      int4 d = dst4[(base >> 2) + it * FRONT_T + tid];
      atomicAdd(&rank[(u32)d.x >> SHIFTC], 1u);
      atomicAdd(&rank[(u32)d.y >> SHIFTC], 1u);
      atomicAdd(&rank[(u32)d.z >> SHIFTC], 1u);
      atomicAdd(&rank[(u32)d.w >> SHIFTC], 1u);
    }
  }
  __syncthreads();

  // exclusive scan of 782 bins: threads 0..195 hold 4 bins each; the wave
  // scan runs on waves 0..3 only (tid<256 guard -> wtot[4] stays in range).
  if (tid < 256) {
    u32 lh[4] = {0u, 0u, 0u, 0u};
    u32 lsum = 0u;
    if (tid < 196) {
      #pragma unroll
      for (int k = 0; k < 4; ++k) {
        int b4 = tid * 4 + k;
        lh[k] = (b4 < NCB) ? rank[b4] : 0u;
        lsum += lh[k];
      }
    }
    u32 v = lsum;
    #pragma unroll
    for (int off = 1; off < 64; off <<= 1) {
      u32 t = __shfl_up(v, off, 64);
      if ((tid & 63) >= off) v += t;
    }
    if ((tid & 63) == 63) wtot[tid >> 6] = v;
    __syncthreads();
    u32 wofs = 0u;
    #pragma unroll
    for (int w = 0; w < 3; ++w) if ((tid >> 6) > w) wofs += wtot[w];
    if (tid < 196) {
      u32 excl = wofs + v - lsum;    // exclusive prefix across threads
      #pragma unroll
      for (int k = 0; k < 4; ++k) {
        int b4 = tid * 4 + k;
        if (b4 < NCB) segst[b4] = excl;
        excl += lh[k];
      }
      if (tid == 195) segst[NCB] = excl;   // chunk total
    }
  } else {
    __syncthreads();                 // match the barrier inside the guard
  }
  __syncthreads();

  // reset rank for the scatter pass (no global reservation needed)
  for (int t = tid; t < NCB; t += FRONT_T) rank[t] = 0u;
  __syncthreads();

  // pass 2: scatter into LDS (sorted by bucket id)
  #pragma unroll
  for (int it = 0; it < CHUNK_C / (FRONT_T * 4); ++it) {
    int e = base + it * (FRONT_T * 4) + tid * 4;
    if (e < N_EDGES) {
      int4 d = dst4[(base >> 2) + it * FRONT_T + tid];
      int4 s = src4[(base >> 2) + it * FRONT_T + tid];
      #pragma unroll
      for (int q = 0; q < 4; ++q) {
        u32 dd = (u32)((q == 0) ? d.x : (q == 1) ? d.y : (q == 2) ? d.z : d.w);
        u32 ss = (u32)((q == 0) ? s.x : (q == 1) ? s.y : (q == 2) ? s.z : s.w);
        u32 cb = dd >> SHIFTC;
        u32 pos = segst[cb] + atomicAdd(&rank[cb], 1u);
        srt[pos] = ((dd & (NBINS - 1u)) << 17) | ss;   // pos < CHUNK_C always
      }
    }
  }
  __syncthreads();

  // write segment table row (783 contiguous u32) + sorted chunk (coalesced)
  for (int k = tid; k <= NCB; k += FRONT_T)
    segt[(size_t)bid * TW + k] = segst[k];
  int total = (int)segst[NCB];
  for (int t = tid; t < total; t += FRONT_T)
    rec[base + t] = srt[t];
}

// Fused front: blocks [0,NBLK_C) bucket edges, [NBLK_C,+NBLK_N) run gemm1.
__global__ __launch_bounds__(FRONT_T) void k_front(
    const int* __restrict__ src, const int* __restrict__ dst,
    u32* __restrict__ rec, u32* __restrict__ segt,
    const float* __restrict__ x, const float* __restrict__ W,
    float* __restrict__ p1, u16* __restrict__ q1b)
{
  if (blockIdx.x < NBLK_C)
    coarse_body(blockIdx.x, threadIdx.x, src, dst, rec, segt);
  else
    gemm_body(blockIdx.x - NBLK_C, threadIdx.x, x, W, p1, q1b);
}

// Segment gather: assumes srt (LDS sorted src), st, en, l in scope.
// Produces s[DIM] = 8-lane-reduced partial sums.
#define SEG_GATHER(QSRC)                                                      \
  float s[DIM];                                                               \
  _Pragma("unroll")                                                           \
  for (int j = 0; j < DIM; ++j) s[j] = 0.f;                                   \
  {                                                                           \
    int k = st + l;                                                           \
    for (; k + 8 < en; k += 16) {                                             \
      int s0 = (int)srt[k], s1 = (int)srt[k + 8];                             \
      const u32* __restrict__ q0 = (const u32*)(QSRC + (size_t)s0 * QB);      \
      const u32* __restrict__ q1 = (const u32*)(QSRC + (size_t)s1 * QB);      \
      uint4 A0 = *(const uint4*)q0; u32 B0 = q0[4];                           \
      uint4 A1 = *(const uint4*)q1; u32 B1 = q1[4];                           \
      s[0] += bl(A0.x) + bl(A1.x); s[1] += bh(A0.x) + bh(A1.x);               \
      s[2] += bl(A0.y) + bl(A1.y); s[3] += bh(A0.y) + bh(A1.y);               \
      s[4] += bl(A0.z) + bl(A1.z); s[5] += bh(A0.z) + bh(A1.z);               \
      s[6] += bl(A0.w) + bl(A1.w); s[7] += bh(A0.w) + bh(A1.w);               \
      s[8] += bl(B0) + bl(B1);     s[9] += bh(B0) + bh(B1);                   \
    }                                                                         \
    if (k < en) {                                                             \
      int s0 = (int)srt[k];                                                   \
      const u32* __restrict__ q0 = (const u32*)(QSRC + (size_t)s0 * QB);      \
      uint4 A0 = *(const uint4*)q0; u32 B0 = q0[4];                           \
      s[0] += bl(A0.x); s[1] += bh(A0.x);                                     \
      s[2] += bl(A0.y); s[3] += bh(A0.y);                                     \
      s[4] += bl(A0.z); s[5] += bh(A0.z);                                     \
      s[6] += bl(A0.w); s[7] += bh(A0.w);                                     \
      s[8] += bl(B0);   s[9] += bh(B0);                                       \
    }                                                                         \
  }                                                                           \
  _Pragma("unroll")                                                           \
  for (int m = 1; m < 8; m <<= 1) {                                           \
    _Pragma("unroll")                                                         \
    for (int j = 0; j < DIM; ++j) s[j] += __shfl_xor(s[j], m, 8);             \
  }

// Layer 1: assemble bucket c from the 391 per-chunk runs (block-scan of
// counts + run gather into LDS), counting-sort by dst-low, persist sorted
// order (sortrec + segg) for k_zpool, gather q1b, epilogue
// h = relu(p1+mean); y = h.wv1, z = h.wv2 (folded W2@Wfc).
__global__ __launch_bounds__(512) void k_lay1(
    const u32* __restrict__ rec, const u32* __restrict__ segt,
    const float* __restrict__ p1, const u16* __restrict__ q1b,
    const float* __restrict__ W2, const float* __restrict__ Wfc,
    float* __restrict__ y, float* __restrict__ z,
    u32* __restrict__ sortrec, u32* __restrict__ segg)
{
  __shared__ u32 lrec[CAPC];          // 18 KB
  __shared__ u32 srt[CAPC];           // 18 KB (doubles as scan buffer)
  __shared__ u32 hist[NBINS];
  __shared__ u32 segst[NBINS + 1];
  __shared__ u32 rank[NBINS];
  __shared__ u32 wtot[2];
  __shared__ u32 bst[NBLK_C];         // per-chunk base within bucket
  __shared__ u32 ntot_s;
  __shared__ float wv[2 * DIM];       // wv[k] = sum_j W2[k][j] * Wfc[j]
  int tid = threadIdx.x;
  int c = blockIdx.x;
  if (tid < 2 * DIM) {
    float sacc = 0.f;
    #pragma unroll
    for (int j = 0; j < DIM; ++j) sacc += W2[tid * DIM + j] * Wfc[j];
    wv[tid] = sacc;
  }
  if (tid < NBINS) { hist[tid] = 0u; rank[tid] = 0u; }
  // per-chunk counts for bucket c -> exclusive scan (Hillis-Steele in srt)
  u32 cnt = 0u;
  if (tid < NBLK_C)
    cnt = segt[(size_t)tid * TW + c + 1] - segt[(size_t)tid * TW + c];
  srt[tid] = cnt;
  __syncthreads();
  for (int off = 1; off < 512; off <<= 1) {
    u32 v = (tid >= off) ? srt[tid - off] : 0u;
    __syncthreads();
    if (tid >= off) srt[tid] += v;
    __syncthreads();
  }
  if (tid < NBLK_C) bst[tid] = srt[tid] - cnt;
  if (tid == NBLK_C - 1) ntot_s = srt[tid];
  __syncthreads();
  int n = min((int)ntot_s, CAPC);
  // gather the 391 runs into lrec (+histogram). 64 groups of 8 lanes.
  {
    int grp = tid >> 3, l = tid & 7;
    for (int b = grp; b < NBLK_C; b += 64) {
      u32 s0 = segt[(size_t)b * TW + c];
      u32 cn = segt[(size_t)b * TW + c + 1] - s0;
      const u32* __restrict__ rp = rec + (size_t)b * CHUNK_C + s0;
      u32 bb = bst[b];
      for (u32 r = l; r < cn; r += 8u) {
        u32 pos = bb + r;
        if (pos < (u32)CAPC) {
          u32 v = rp[r];
          lrec[pos] = v;
          atomicAdd(&hist[(v >> 17) & (NBINS - 1u)], 1u);
        }
      }
    }
  }
  __syncthreads();
  // 128-bin exclusive scan: intra-wave shfl scan + cross-wave offset
  if (tid < NBINS) {
    u32 h = hist[tid];
    u32 v = h;
    #pragma unroll
    for (int off = 1; off < 64; off <<= 1) {
      u32 t = __shfl_up(v, off, 64);
      if ((tid & 63) >= off) v += t;
    }
    if ((tid & 63) == 63) wtot[tid >> 6] = v;
    segst[tid] = v - h;
  }
  __syncthreads();
  if (tid >= 64 && tid < NBINS) segst[tid] += wtot[0];
  if (tid == 0) segst[NBINS] = wtot[0] + wtot[1];
  __syncthreads();
  for (int r = tid; r < n; r += 512) {
    u32 v = lrec[r];
    u32 dl = (v >> 17) & (NBINS - 1u);
    u32 pos = segst[dl] + atomicAdd(&rank[dl], 1u);
    srt[pos] = v & 0x1FFFFu;
  }
  __syncthreads();
  // persist sorted order + segment table (k_zpool streams them)
  for (int r = tid; r < n; r += 512) sortrec[(size_t)c * CAPC + r] = srt[r];
  if (tid <= NBINS) segg[(size_t)c * SEGW + tid] = segst[tid];
  // gather + epilogue: 64 groups of 8 lanes, 2 rounds cover 128 nodes
  int g0 = tid >> 3, l = tid & 7;
  #pragma unroll
  for (int rd = 0; rd < 2; ++rd) {
    int g2 = rd * 64 + g0;
    int st = (int)segst[g2], en = (int)segst[g2 + 1];
    SEG_GATHER(q1b)
    if (l == 0) {
      int i = c * NBINS + g2;
      if (i < N_NODES) {
        float dinv = 1.0f / fmaxf((float)(en - st), 1.0f);
        const float* __restrict__ pr = p1 + (size_t)i * DIM;
        float yv = 0.f, zv = 0.f;
        #pragma unroll
        for (int j = 0; j < DIM; ++j) {
          float h = fmaxf(pr[j] + s[j] * dinv, 0.0f);
          yv += h * wv[j];
          zv += h * wv[DIM + j];
        }
        y[i] = yv;
        z[i] = zv;
      }
    }
  }
}

// Merged layer2+pool: one block per graph. For each node in the graph's
// contiguous range, stream its persisted sorted segment (segg lookup),
// gather z[src] (4B, L2-resident 400KB table), val = y + mean(z-seg);
// block-reduce, sigmoid -> out[g]. Zero atomics, no LDS staging.
__global__ __launch_bounds__(256) void k_zpool(
    const u32* __restrict__ sortrec, const u32* __restrict__ segg,
    const float* __restrict__ y, const float* __restrict__ z,
    const int* __restrict__ batch, float* __restrict__ out)
{
  __shared__ float wsum[4];
  int g = blockIdx.x;
  int tid = threadIdx.x;
  int lo = 0, hi = N_NODES;
  while (lo < hi) { int m = (lo + hi) >> 1; if (batch[m] < g) lo = m + 1; else hi = m; }
  int start = lo;
  hi = N_NODES;
  while (lo < hi) { int m = (lo + hi) >> 1; if (batch[m] < g + 1) lo = m + 1; else hi = m; }
  int end = lo;
  int grp = tid >> 3, l = tid & 7;    // 32 groups of 8 lanes
  float acc = 0.f;
  for (int i = start + grp; i < end; i += 32) {
    int c = i >> SHIFTC, bin = i & (NBINS - 1);
    u32 st = segg[(size_t)c * SEGW + bin];
    u32 en = segg[(size_t)c * SEGW + bin + 1];
    const u32* __restrict__ rc = sortrec + (size_t)c * CAPC;
    float sc = 0.f;
    for (u32 k = st + l; k < en; k += 8u) sc += z[rc[k]];
    #pragma unroll
    for (int m = 1; m < 8; m <<= 1) sc += __shfl_xor(sc, m, 8);
    if (l == 0) acc += y[i] + sc / fmaxf((float)(en - st), 1.0f);
  }
  // block reduction (non-l0 lanes hold 0 after masking)
  if (l != 0) acc = 0.f;
  #pragma unroll
  for (int m = 1; m < 64; m <<= 1) acc += __shfl_xor(acc, m, 64);
  if ((tid & 63) == 0) wsum[tid >> 6] = acc;
  __syncthreads();
  if (tid == 0) {
    float tot = wsum[0] + wsum[1] + wsum[2] + wsum[3];
    float gm = tot / fmaxf((float)(end - start), 1.0f);
    out[g] = 1.0f / (1.0f + expf(-gm));
  }
}

extern "C" void kernel_launch(void* const* d_in, const int* in_sizes, int n_in,
                              void* d_out, int out_size, void* d_ws, size_t ws_size,
                              hipStream_t stream)
{
  const float* x     = (const float*)d_in[0];
  const int*   ei    = (const int*)d_in[1];
  const int*   batch = (const int*)d_in[2];
  const float* W1    = (const float*)d_in[3];
  const float* W2    = (const float*)d_in[4];
  const float* Wfc   = (const float*)d_in[5];
  float* out = (float*)d_out;

  const int* src = ei;            // edge_index[0]
  const int* dst = ei + N_EDGES;  // edge_index[1]

  // ---- workspace layout (u32 element offsets), total ~36.9 MB.
  // NOTHING needs zero-init: segt fully written by front, sortrec/segg by
  // lay1, y/z by lay1 -> no memset dispatch.
  u32* wsp = (u32*)d_ws;
  u32* rec     = wsp;                                 // 391*8192 = 3,203,072
  u32* segt    = rec + (size_t)NBLK_C * CHUNK_C;      // 391*783 (pad 306,176)
  u32* sortrec = segt + 306176;                       // 782*4608 = 3,603,456
  u32* segg    = sortrec + (size_t)NCB * CAPC;        // 782*129 (pad 100,928)
  u32* after   = segg + 100928;
  u16*   q1b = (u16*)after;                           // 800,000 u32
  float* p1  = (float*)(after + 800000);              // 1,000,000 u32
  float* y   = (float*)(after + 1800000);             // 100,096 u32
  float* z   = (float*)(after + 1900096);             // 100,096 u32

  k_front<<<NBLK_C + NBLK_N, FRONT_T, 0, stream>>>(src, dst, rec, segt,
                                                   x, W1, p1, q1b);
  k_lay1<<<NCB, 512, 0, stream>>>(rec, segt, p1, q1b, W2, Wfc, y, z,
                                  sortrec, segg);
  k_zpool<<<B_GRAPHS, 256, 0, stream>>>(sortrec, segg, y, z, batch, out);
}